// Round 2
// baseline (2300.979 us; speedup 1.0000x reference)
//
#include <hip/hip_runtime.h>
#include <hip/hip_bf16.h>

typedef __bf16 bf16;
typedef __bf16 bf16x8 __attribute__((ext_vector_type(8)));
typedef float f32x4 __attribute__((ext_vector_type(4)));

#define B_ 2
#define S_ 1024
#define D_ 1024
#define L_ 8
#define HQ_ 16
#define HK_ 4
#define DH_ 64
#define FF_ 2816
#define V_ 32000

// ---------------- embedding gather ----------------
__global__ __launch_bounds__(256) void embed_k(const int* __restrict__ toks,
                                               const float* __restrict__ emb,
                                               float* __restrict__ h) {
  int row = blockIdx.x;
  int tok = toks[row];
  f32x4 v = *(const f32x4*)&emb[(size_t)tok * D_ + threadIdx.x * 4];
  *(f32x4*)&h[(size_t)row * D_ + threadIdx.x * 4] = v;
}

// ---------------- rope table: tab[s][d] = {cos, sin} ----------------
__global__ __launch_bounds__(256) void ropetab_k(float* __restrict__ tab) {
  int i = blockIdx.x * 256 + threadIdx.x;
  if (i >= S_ * 32) return;
  int d = i & 31, s = i >> 5;
  float f = expf(-(2.0f * d / 64.0f) * logf(500000.0f));
  float ang = (float)s * f;
  tab[i * 2]     = cosf(ang);
  tab[i * 2 + 1] = sinf(ang);
}

// ---------------- rmsnorm: fp32 in -> bf16 out ----------------
__global__ __launch_bounds__(256) void rmsnorm_k(const float* __restrict__ x,
                                                 const float* __restrict__ w,
                                                 bf16* __restrict__ out) {
  int row = blockIdx.x;
  const float* xr = x + (size_t)row * D_;
  int base = threadIdx.x * 4;
  f32x4 v = *(const f32x4*)&xr[base];
  float ss = v[0]*v[0] + v[1]*v[1] + v[2]*v[2] + v[3]*v[3];
  for (int m = 1; m < 64; m <<= 1) ss += __shfl_xor(ss, m, 64);
  __shared__ float partial[4];
  if ((threadIdx.x & 63) == 0) partial[threadIdx.x >> 6] = ss;
  __syncthreads();
  float tot = partial[0] + partial[1] + partial[2] + partial[3];
  float rr = rsqrtf(tot * (1.0f / D_) + 1e-5f);
  f32x4 wv = *(const f32x4*)&w[base];
  bf16* o = out + (size_t)row * D_ + base;
  o[0] = (bf16)(v[0] * rr * wv[0]);
  o[1] = (bf16)(v[1] * rr * wv[1]);
  o[2] = (bf16)(v[2] * rr * wv[2]);
  o[3] = (bf16)(v[3] * rr * wv[3]);
}

// ---------------- transpose + fp32->bf16:  src[K][N] -> dst[N][K] ----------------
__global__ __launch_bounds__(256) void transpose_cvt(const float* __restrict__ src,
                                                     bf16* __restrict__ dst,
                                                     int K, int N,
                                                     long long srcStride, long long dstStride) {
  __shared__ float tile[32][33];
  int bx = blockIdx.x, by = blockIdx.y, z = blockIdx.z;
  src += (size_t)z * srcStride;
  dst += (size_t)z * dstStride;
  int tx = threadIdx.x & 31, ty = threadIdx.x >> 5;
#pragma unroll
  for (int i = 0; i < 4; ++i) {
    int r = ty + i * 8;
    tile[r][tx] = src[(size_t)(by * 32 + r) * N + bx * 32 + tx];
  }
  __syncthreads();
#pragma unroll
  for (int i = 0; i < 4; ++i) {
    int r = ty + i * 8;
    dst[(size_t)(bx * 32 + r) * K + by * 32 + tx] = (bf16)tile[tx][r];
  }
}

// ---------------- GEMM: C[M][N] = A[M][K](bf16) * BT[N][K](bf16) ----------------
// m97 structure: async global_load_lds (16B/lane), linear LDS, 2-barrier K-loop.
// Grid: x = M/128 (column-panel execution for B-tile L2 reuse), y = N/128.
// EPI 0: fp32 out.  EPI 1: fp32 out = acc + R (residual, may alias Cout).  EPI 2: bf16 out.
template <int EPI>
__global__ __launch_bounds__(256) void gemm_bt(const bf16* __restrict__ A,
                                               const bf16* __restrict__ BT,
                                               void* __restrict__ Cout,
                                               const float* __restrict__ R,
                                               int M, int N, int K) {
  __shared__ bf16 As[128 * 64];
  __shared__ bf16 Bs[128 * 64];
  const int t = threadIdx.x;
  const int w = t >> 6, l = t & 63;
  const int l15 = l & 15, l4 = l >> 4;
  const int bm = blockIdx.x * 128, bn = blockIdx.y * 128;
  const int wr = w >> 1, wc = w & 1;

  // staging coords: element-chunk e = i*256 + t covers row = e>>3, col8 = (e&7)*8
  const int srow = t >> 3, scol = (t & 7) * 8;          // within i-th slab rows advance by 32
  const bf16* ag = &A[(size_t)(bm + srow) * K + scol];
  const bf16* bg = &BT[(size_t)(bn + srow) * K + scol];
  // wave-uniform LDS base (elems): (i*256 + w*64) * 8
  const int ldsbase = (t & 192) * 8;

  f32x4 acc[4][4] = {};

  for (int k0 = 0; k0 < K; k0 += 64) {
#pragma unroll
    for (int i = 0; i < 4; ++i) {
      __builtin_amdgcn_global_load_lds(
          (const __attribute__((address_space(1))) void*)(ag + (size_t)(i * 32) * K + k0),
          (__attribute__((address_space(3))) void*)&As[i * 2048 + ldsbase], 16, 0, 0);
      __builtin_amdgcn_global_load_lds(
          (const __attribute__((address_space(1))) void*)(bg + (size_t)(i * 32) * K + k0),
          (__attribute__((address_space(3))) void*)&Bs[i * 2048 + ldsbase], 16, 0, 0);
    }
    __syncthreads();
#pragma unroll
    for (int kc = 0; kc < 2; ++kc) {
      bf16x8 af[4], bfr[4];
#pragma unroll
      for (int m = 0; m < 4; ++m)
        af[m] = *(const bf16x8*)&As[(wr * 64 + m * 16 + l15) * 64 + kc * 32 + l4 * 8];
#pragma unroll
      for (int n = 0; n < 4; ++n)
        bfr[n] = *(const bf16x8*)&Bs[(wc * 64 + n * 16 + l15) * 64 + kc * 32 + l4 * 8];
#pragma unroll
      for (int m = 0; m < 4; ++m)
#pragma unroll
        for (int n = 0; n < 4; ++n)
          acc[m][n] = __builtin_amdgcn_mfma_f32_16x16x32_bf16(af[m], bfr[n], acc[m][n], 0, 0, 0);
    }
    __syncthreads();
  }

#pragma unroll
  for (int m = 0; m < 4; ++m)
#pragma unroll
    for (int n = 0; n < 4; ++n)
#pragma unroll
      for (int r = 0; r < 4; ++r) {
        int row = bm + wr * 64 + m * 16 + l4 * 4 + r;
        int col = bn + wc * 64 + n * 16 + l15;
        size_t ix = (size_t)row * N + col;
        float v = acc[m][n][r];
        if (EPI == 0)      ((float*)Cout)[ix] = v;
        else if (EPI == 1) ((float*)Cout)[ix] = v + R[ix];
        else               ((bf16*)Cout)[ix] = (bf16)v;
      }
}

// ---------------- rope on q: qkv[B*S][1536] -> q_r[b,h,s,dh] bf16 ----------------
__global__ __launch_bounds__(256) void rope_q_k(const bf16* __restrict__ qkv,
                                                const float* __restrict__ tab,
                                                bf16* __restrict__ q_r) {
  int i = blockIdx.x * 256 + threadIdx.x;     // pair index, 2^20 total
  int d = i & 31, h = (i >> 5) & 15, s = (i >> 9) & 1023, b = i >> 19;
  size_t src = (size_t)(b * S_ + s) * 1536 + h * 64 + 2 * d;
  float a  = (float)qkv[src];
  float bb = (float)qkv[src + 1];
  float c  = tab[(s * 32 + d) * 2];
  float sn = tab[(s * 32 + d) * 2 + 1];
  size_t o = ((size_t)((b * HQ_ + h) * S_ + s)) * 64 + 2 * d;
  q_r[o]     = (bf16)(a * c - bb * sn);
  q_r[o + 1] = (bf16)(a * sn + bb * c);
}

// ---------------- rope on k ----------------
__global__ __launch_bounds__(256) void rope_k_k(const bf16* __restrict__ qkv,
                                                const float* __restrict__ tab,
                                                bf16* __restrict__ k_r) {
  int i = blockIdx.x * 256 + threadIdx.x;     // 2^18 total
  int d = i & 31, h = (i >> 5) & 3, s = (i >> 7) & 1023, b = i >> 17;
  size_t src = (size_t)(b * S_ + s) * 1536 + 1024 + h * 64 + 2 * d;
  float a  = (float)qkv[src];
  float bb = (float)qkv[src + 1];
  float c  = tab[(s * 32 + d) * 2];
  float sn = tab[(s * 32 + d) * 2 + 1];
  size_t o = ((size_t)((b * HK_ + h) * S_ + s)) * 64 + 2 * d;
  k_r[o]     = (bf16)(a * c - bb * sn);
  k_r[o + 1] = (bf16)(a * sn + bb * c);
}

// ---------------- v transpose: qkv v-cols -> vT[b,h,dh,s] bf16 ----------------
__global__ __launch_bounds__(256) void vtr_k(const bf16* __restrict__ qkv,
                                             bf16* __restrict__ vT) {
  int i = blockIdx.x * 256 + threadIdx.x;     // 2^19 total
  int s = i & 1023, dh = (i >> 10) & 63, h = (i >> 16) & 3, b = i >> 18;
  vT[((size_t)((b * HK_ + h) * 64 + dh)) * S_ + s] =
      qkv[(size_t)(b * S_ + s) * 1536 + 1280 + h * 64 + dh];
}

// ---------------- flash attention (causal, GQA) ----------------
__global__ __launch_bounds__(256) void attn_k(const bf16* __restrict__ q_r,
                                              const bf16* __restrict__ k_r,
                                              const bf16* __restrict__ vT,
                                              bf16* __restrict__ o) {
  __shared__ bf16 k_lds[64 * 64];       // [kpos][dh]
  __shared__ bf16 v_lds[64 * 64];       // [dh][kpos]
  __shared__ bf16 p_lds[4][16 * 72];    // per-wave [16 q][64 k + pad]
  int t = threadIdx.x, w = t >> 6, l = t & 63, l15 = l & 15, l4 = l >> 4;
  int qt = blockIdx.x & 15, head = (blockIdx.x >> 4) & 15, b = blockIdx.x >> 8;
  int kvh = head >> 2;
  const bf16* qh = q_r + ((size_t)(b * HQ_ + head)) * S_ * 64;
  const bf16* kh = k_r + ((size_t)(b * HK_ + kvh)) * S_ * 64;
  const bf16* vh = vT + ((size_t)(b * HK_ + kvh)) * 64 * S_;
  int q0 = qt * 64 + w * 16;

  bf16x8 aq[2];
  aq[0] = *(const bf16x8*)&qh[(size_t)(q0 + l15) * 64 + l4 * 8];
  aq[1] = *(const bf16x8*)&qh[(size_t)(q0 + l15) * 64 + 32 + l4 * 8];

  f32x4 acc_o[4] = {};
  float m_run[4], l_run[4];
#pragma unroll
  for (int r = 0; r < 4; ++r) { m_run[r] = -1e30f; l_run[r] = 0.f; }

  for (int kt = 0; kt <= qt; ++kt) {
    {
      const bf16* src = kh + kt * 4096;
#pragma unroll
      for (int i = 0; i < 2; ++i) {
        int c = i * 256 + t;
        *(bf16x8*)&k_lds[c * 8] = *(const bf16x8*)&src[c * 8];
      }
#pragma unroll
      for (int i = 0; i < 2; ++i) {
        int c = i * 256 + t;
        int row = c >> 3, col8 = (c & 7) * 8;
        *(bf16x8*)&v_lds[row * 64 + col8] = *(const bf16x8*)&vh[(size_t)row * S_ + kt * 64 + col8];
      }
    }
    __syncthreads();

    // QK^T
    f32x4 sc[4];
#pragma unroll
    for (int nt = 0; nt < 4; ++nt) {
      f32x4 a = {};
#pragma unroll
      for (int kc = 0; kc < 2; ++kc) {
        bf16x8 bk = *(const bf16x8*)&k_lds[(nt * 16 + l15) * 64 + kc * 32 + l4 * 8];
        a = __builtin_amdgcn_mfma_f32_16x16x32_bf16(aq[kc], bk, a, 0, 0, 0);
      }
      sc[nt] = a;
    }

    bool diag = (kt == qt);
#pragma unroll
    for (int r = 0; r < 4; ++r) {
      float mx = -1e30f;
#pragma unroll
      for (int nt = 0; nt < 4; ++nt) {
        float s = sc[nt][r] * 0.125f;
        if (diag) {
          int kj = nt * 16 + l15;
          int qi = w * 16 + l4 * 4 + r;
          if (kj > qi) s = -1e30f;
        }
        sc[nt][r] = s;
        mx = fmaxf(mx, s);
      }
      mx = fmaxf(mx, __shfl_xor(mx, 1, 64));
      mx = fmaxf(mx, __shfl_xor(mx, 2, 64));
      mx = fmaxf(mx, __shfl_xor(mx, 4, 64));
      mx = fmaxf(mx, __shfl_xor(mx, 8, 64));
      float mn = fmaxf(m_run[r], mx);
      float scale = __expf(m_run[r] - mn);
      m_run[r] = mn;
      float rs = 0.f;
#pragma unroll
      for (int nt = 0; nt < 4; ++nt) {
        float p = __expf(sc[nt][r] - mn);
        sc[nt][r] = p;
        rs += p;
      }
      rs += __shfl_xor(rs, 1, 64);
      rs += __shfl_xor(rs, 2, 64);
      rs += __shfl_xor(rs, 4, 64);
      rs += __shfl_xor(rs, 8, 64);
      l_run[r] = l_run[r] * scale + rs;
#pragma unroll
      for (int nt = 0; nt < 4; ++nt) acc_o[nt][r] *= scale;
    }

    // P -> LDS (per-wave region), then PV
#pragma unroll
    for (int nt = 0; nt < 4; ++nt)
#pragma unroll
      for (int r = 0; r < 4; ++r)
        p_lds[w][(l4 * 4 + r) * 72 + nt * 16 + l15] = (bf16)sc[nt][r];
    asm volatile("s_waitcnt lgkmcnt(0)" ::: "memory");
    __builtin_amdgcn_sched_barrier(0);

#pragma unroll
    for (int kc = 0; kc < 2; ++kc) {
      bf16x8 pf = *(const bf16x8*)&p_lds[w][l15 * 72 + kc * 32 + l4 * 8];
#pragma unroll
      for (int nt = 0; nt < 4; ++nt) {
        bf16x8 vf = *(const bf16x8*)&v_lds[(nt * 16 + l15) * 64 + kc * 32 + l4 * 8];
        acc_o[nt] = __builtin_amdgcn_mfma_f32_16x16x32_bf16(pf, vf, acc_o[nt], 0, 0, 0);
      }
    }
    __syncthreads();
  }

#pragma unroll
  for (int nt = 0; nt < 4; ++nt)
#pragma unroll
    for (int r = 0; r < 4; ++r) {
      float ov = acc_o[nt][r] / l_run[r];
      int s = qt * 64 + w * 16 + l4 * 4 + r;
      o[((size_t)(b * S_ + s)) * D_ + head * 64 + nt * 16 + l15] = (bf16)ov;
    }
}

// ---------------- silu(ff1) * ff3 -> gate bf16 ----------------
__global__ __launch_bounds__(256) void silumul_k(const bf16* __restrict__ ff,
                                                 bf16* __restrict__ gate) {
  int p = blockIdx.x * 256 + threadIdx.x;    // 720896 total
  int row = p / 352;
  int j = (p % 352) * 8;
  bf16x8 a = *(const bf16x8*)&ff[(size_t)row * 5632 + j];
  bf16x8 c = *(const bf16x8*)&ff[(size_t)row * 5632 + 2816 + j];
  bf16x8 g;
#pragma unroll
  for (int i = 0; i < 8; ++i) {
    float x = (float)a[i];
    float s = x / (1.0f + __expf(-x));
    g[i] = (bf16)(s * (float)c[i]);
  }
  *(bf16x8*)&gate[(size_t)row * 2816 + j] = g;
}

// =======================================================================
extern "C" void kernel_launch(void* const* d_in, const int* in_sizes, int n_in,
                              void* d_out, int out_size, void* d_ws, size_t ws_size,
                              hipStream_t stream) {
  const int* tokens  = (const int*)d_in[0];
  const float* tok_emb = (const float*)d_in[2];
  const float* wq = (const float*)d_in[3];
  const float* wk = (const float*)d_in[4];
  const float* wv = (const float*)d_in[5];
  const float* wo = (const float*)d_in[6];
  const float* w1 = (const float*)d_in[7];
  const float* w2 = (const float*)d_in[8];
  const float* w3 = (const float*)d_in[9];
  const float* anw = (const float*)d_in[10];
  const float* fnw = (const float*)d_in[11];
  const float* finw = (const float*)d_in[12];
  const float* outw = (const float*)d_in[13];

  auto al = [](size_t x) { return (x + 255) & ~(size_t)255; };
  const size_t WTB   = 11272192ull * 2;   // per-layer transposed weights (bf16)
  const size_t OUTWTB = (size_t)V_ * D_ * 2;
  const size_t HB   = (size_t)B_ * S_ * D_ * 4;
  const size_t XBB  = (size_t)B_ * S_ * D_ * 2;
  const size_t QKVB = (size_t)B_ * S_ * 1536 * 2;
  const size_t QRB  = (size_t)B_ * HQ_ * S_ * 64 * 2;
  const size_t KRB  = (size_t)B_ * HK_ * S_ * 64 * 2;
  const size_t OB   = (size_t)B_ * S_ * D_ * 2;
  const size_t FFB  = (size_t)B_ * S_ * 5632 * 2;
  const size_t GATEB = (size_t)B_ * S_ * 2816 * 2;
  const size_t TABB = (size_t)S_ * 32 * 2 * 4;

  size_t fixed = al(OUTWTB) + al(HB) + al(XBB) + al(QKVB) + al(QRB) + al(KRB) + al(KRB) +
                 al(OB) + al(FFB) + al(GATEB) + al(TABB);
  bool allup = ws_size >= fixed + 8 * al(WTB) + 4096;
  int nslots = allup ? 8 : 1;

  char* p = (char*)d_ws;
  bf16* wT    = (bf16*)p; p += (size_t)nslots * al(WTB);
  bf16* outwT = (bf16*)p; p += al(OUTWTB);
  float* h    = (float*)p; p += al(HB);
  bf16* xb    = (bf16*)p; p += al(XBB);
  bf16* qkv   = (bf16*)p; p += al(QKVB);
  bf16* q_r   = (bf16*)p; p += al(QRB);
  bf16* k_r   = (bf16*)p; p += al(KRB);
  bf16* vTb   = (bf16*)p; p += al(KRB);
  bf16* ob    = (bf16*)p; p += al(OB);
  bf16* ff    = (bf16*)p; p += al(FFB);
  bf16* gate  = (bf16*)p; p += al(GATEB);
  float* tab  = (float*)p; p += al(TABB);

  const size_t WTS = al(WTB) / 2;   // slot stride in elems
  // offsets within a layer slot (elems)
  const size_t OFF_QKV = 0;
  const size_t OFF_WK  = 1024ull * 1024;
  const size_t OFF_WV  = 1280ull * 1024;
  const size_t OFF_WO  = 1572864ull;
  const size_t OFF_W13 = 2621440ull;
  const size_t OFF_W3  = 2621440ull + 2816ull * 1024;
  const size_t OFF_W2  = 8388608ull;

  auto tr = [&](const float* src, size_t srcStride, bf16* dst, size_t dstStride,
                int Kd, int Nd, int layers) {
    transpose_cvt<<<dim3(Nd / 32, Kd / 32, layers), 256, 0, stream>>>(
        src, dst, Kd, Nd, (long long)srcStride, (long long)dstStride);
  };

  // GEMM launcher: grid.x = M/128 (column-panel order), grid.y = N/128
  auto gemm = [&](auto tag, const bf16* A, const bf16* Bt, void* C, const float* R,
                  int M, int N, int K) {
    gemm_bt<decltype(tag)::value><<<dim3(M / 128, N / 128), 256, 0, stream>>>(A, Bt, C, R, M, N, K);
  };

  ropetab_k<<<128, 256, 0, stream>>>(tab);
  embed_k<<<B_ * S_, 256, 0, stream>>>(tokens, tok_emb, h);
  tr(outw, 0, outwT, 0, 1024, 32000, 1);

  if (allup) {
    tr(wq, 1024 * 1024, wT + OFF_QKV, WTS, 1024, 1024, 8);
    tr(wk, 1024 * 256,  wT + OFF_WK,  WTS, 1024, 256, 8);
    tr(wv, 1024 * 256,  wT + OFF_WV,  WTS, 1024, 256, 8);
    tr(wo, 1024 * 1024, wT + OFF_WO,  WTS, 1024, 1024, 8);
    tr(w1, 1024 * 2816, wT + OFF_W13, WTS, 1024, 2816, 8);
    tr(w3, 1024 * 2816, wT + OFF_W3,  WTS, 1024, 2816, 8);
    tr(w2, 2816 * 1024, wT + OFF_W2,  WTS, 2816, 1024, 8);
  }

  for (int l = 0; l < L_; ++l) {
    bf16* wtl = wT + (allup ? (size_t)l * WTS : 0);
    if (!allup) {
      tr(wq + (size_t)l * 1024 * 1024, 0, wtl + OFF_QKV, 0, 1024, 1024, 1);
      tr(wk + (size_t)l * 1024 * 256,  0, wtl + OFF_WK,  0, 1024, 256, 1);
      tr(wv + (size_t)l * 1024 * 256,  0, wtl + OFF_WV,  0, 1024, 256, 1);
      tr(wo + (size_t)l * 1024 * 1024, 0, wtl + OFF_WO,  0, 1024, 1024, 1);
      tr(w1 + (size_t)l * 1024 * 2816, 0, wtl + OFF_W13, 0, 1024, 2816, 1);
      tr(w3 + (size_t)l * 1024 * 2816, 0, wtl + OFF_W3,  0, 1024, 2816, 1);
      tr(w2 + (size_t)l * 2816 * 1024, 0, wtl + OFF_W2,  0, 2816, 1024, 1);
    }

    rmsnorm_k<<<B_ * S_, 256, 0, stream>>>(h, anw + l * D_, xb);
    gemm_bt<2><<<dim3(16, 12), 256, 0, stream>>>(xb, wtl + OFF_QKV, qkv, nullptr, 2048, 1536, 1024);
    rope_q_k<<<4096, 256, 0, stream>>>(qkv, tab, q_r);
    rope_k_k<<<1024, 256, 0, stream>>>(qkv, tab, k_r);
    vtr_k<<<2048, 256, 0, stream>>>(qkv, vTb);
    attn_k<<<B_ * HQ_ * (S_ / 64), 256, 0, stream>>>(q_r, k_r, vTb, ob);
    gemm_bt<1><<<dim3(16, 8), 256, 0, stream>>>(ob, wtl + OFF_WO, h, h, 2048, 1024, 1024);
    rmsnorm_k<<<B_ * S_, 256, 0, stream>>>(h, fnw + l * D_, xb);
    gemm_bt<2><<<dim3(16, 44), 256, 0, stream>>>(xb, wtl + OFF_W13, ff, nullptr, 2048, 5632, 1024);
    silumul_k<<<2816, 256, 0, stream>>>(ff, gate);
    gemm_bt<1><<<dim3(16, 8), 256, 0, stream>>>(gate, wtl + OFF_W2, h, h, 2048, 1024, 2816);
  }

  rmsnorm_k<<<B_ * S_, 256, 0, stream>>>(h, finw, xb);
  gemm_bt<0><<<dim3(16, 250), 256, 0, stream>>>(xb, outwT, d_out, nullptr, 2048, 32000, 1024);
}

// Round 3
// 2075.161 us; speedup vs baseline: 1.1088x; 1.1088x over previous
//
#include <hip/hip_runtime.h>
#include <hip/hip_bf16.h>

typedef __bf16 bf16;
typedef __bf16 bf16x8 __attribute__((ext_vector_type(8)));
typedef float f32x4 __attribute__((ext_vector_type(4)));

#define B_ 2
#define S_ 1024
#define D_ 1024
#define L_ 8
#define HQ_ 16
#define HK_ 4
#define DH_ 64
#define FF_ 2816
#define V_ 32000

// ---------------- embedding gather ----------------
__global__ __launch_bounds__(256) void embed_k(const int* __restrict__ toks,
                                               const float* __restrict__ emb,
                                               float* __restrict__ h) {
  int row = blockIdx.x;
  int tok = toks[row];
  f32x4 v = *(const f32x4*)&emb[(size_t)tok * D_ + threadIdx.x * 4];
  *(f32x4*)&h[(size_t)row * D_ + threadIdx.x * 4] = v;
}

// ---------------- rope table: tab[s][d] = {cos, sin} ----------------
__global__ __launch_bounds__(256) void ropetab_k(float* __restrict__ tab) {
  int i = blockIdx.x * 256 + threadIdx.x;
  if (i >= S_ * 32) return;
  int d = i & 31, s = i >> 5;
  float f = expf(-(2.0f * d / 64.0f) * logf(500000.0f));
  float ang = (float)s * f;
  tab[i * 2]     = cosf(ang);
  tab[i * 2 + 1] = sinf(ang);
}

// ---------------- rmsnorm: fp32 in -> bf16 out ----------------
__global__ __launch_bounds__(256) void rmsnorm_k(const float* __restrict__ x,
                                                 const float* __restrict__ w,
                                                 bf16* __restrict__ out) {
  int row = blockIdx.x;
  const float* xr = x + (size_t)row * D_;
  int base = threadIdx.x * 4;
  f32x4 v = *(const f32x4*)&xr[base];
  float ss = v[0]*v[0] + v[1]*v[1] + v[2]*v[2] + v[3]*v[3];
  for (int m = 1; m < 64; m <<= 1) ss += __shfl_xor(ss, m, 64);
  __shared__ float partial[4];
  if ((threadIdx.x & 63) == 0) partial[threadIdx.x >> 6] = ss;
  __syncthreads();
  float tot = partial[0] + partial[1] + partial[2] + partial[3];
  float rr = rsqrtf(tot * (1.0f / D_) + 1e-5f);
  f32x4 wv = *(const f32x4*)&w[base];
  bf16* o = out + (size_t)row * D_ + base;
  o[0] = (bf16)(v[0] * rr * wv[0]);
  o[1] = (bf16)(v[1] * rr * wv[1]);
  o[2] = (bf16)(v[2] * rr * wv[2]);
  o[3] = (bf16)(v[3] * rr * wv[3]);
}

// ---------------- transpose + fp32->bf16:  src[K][N] -> dst[N][K] ----------------
__global__ __launch_bounds__(256) void transpose_cvt(const float* __restrict__ src,
                                                     bf16* __restrict__ dst,
                                                     int K, int N,
                                                     long long srcStride, long long dstStride) {
  __shared__ float tile[32][33];
  int bx = blockIdx.x, by = blockIdx.y, z = blockIdx.z;
  src += (size_t)z * srcStride;
  dst += (size_t)z * dstStride;
  int tx = threadIdx.x & 31, ty = threadIdx.x >> 5;
#pragma unroll
  for (int i = 0; i < 4; ++i) {
    int r = ty + i * 8;
    tile[r][tx] = src[(size_t)(by * 32 + r) * N + bx * 32 + tx];
  }
  __syncthreads();
#pragma unroll
  for (int i = 0; i < 4; ++i) {
    int r = ty + i * 8;
    dst[(size_t)(bx * 32 + r) * K + by * 32 + tx] = (bf16)tile[tx][r];
  }
}

// ---------------- 128x128 2-phase GEMM (small-N shapes) ----------------
// C[M][N] = A[M][K](bf16) * BT[N][K](bf16)
// EPI 0: fp32 out.  EPI 1: fp32 out = acc + R.  EPI 2: bf16 out.
template <int EPI>
__global__ __launch_bounds__(256) void gemm_bt(const bf16* __restrict__ A,
                                               const bf16* __restrict__ BT,
                                               void* __restrict__ Cout,
                                               const float* __restrict__ R,
                                               int M, int N, int K) {
  __shared__ bf16 As[128 * 64];
  __shared__ bf16 Bs[128 * 64];
  const int t = threadIdx.x;
  const int w = t >> 6, l = t & 63;
  const int l15 = l & 15, l4 = l >> 4;
  const int bm = blockIdx.x * 128, bn = blockIdx.y * 128;
  const int wr = w >> 1, wc = w & 1;

  const int srow = t >> 3, scol = (t & 7) * 8;
  const bf16* ag = &A[(size_t)(bm + srow) * K + scol];
  const bf16* bg = &BT[(size_t)(bn + srow) * K + scol];
  const int ldsbase = (t & 192) * 8;

  f32x4 acc[4][4] = {};

  for (int k0 = 0; k0 < K; k0 += 64) {
#pragma unroll
    for (int i = 0; i < 4; ++i) {
      __builtin_amdgcn_global_load_lds(
          (const __attribute__((address_space(1))) void*)(ag + (size_t)(i * 32) * K + k0),
          (__attribute__((address_space(3))) void*)&As[i * 2048 + ldsbase], 16, 0, 0);
      __builtin_amdgcn_global_load_lds(
          (const __attribute__((address_space(1))) void*)(bg + (size_t)(i * 32) * K + k0),
          (__attribute__((address_space(3))) void*)&Bs[i * 2048 + ldsbase], 16, 0, 0);
    }
    __syncthreads();
#pragma unroll
    for (int kc = 0; kc < 2; ++kc) {
      bf16x8 af[4], bfr[4];
#pragma unroll
      for (int m = 0; m < 4; ++m)
        af[m] = *(const bf16x8*)&As[(wr * 64 + m * 16 + l15) * 64 + kc * 32 + l4 * 8];
#pragma unroll
      for (int n = 0; n < 4; ++n)
        bfr[n] = *(const bf16x8*)&Bs[(wc * 64 + n * 16 + l15) * 64 + kc * 32 + l4 * 8];
#pragma unroll
      for (int m = 0; m < 4; ++m)
#pragma unroll
        for (int n = 0; n < 4; ++n)
          acc[m][n] = __builtin_amdgcn_mfma_f32_16x16x32_bf16(af[m], bfr[n], acc[m][n], 0, 0, 0);
    }
    __syncthreads();
  }

#pragma unroll
  for (int m = 0; m < 4; ++m)
#pragma unroll
    for (int n = 0; n < 4; ++n)
#pragma unroll
      for (int r = 0; r < 4; ++r) {
        int row = bm + wr * 64 + m * 16 + l4 * 4 + r;
        int col = bn + wc * 64 + n * 16 + l15;
        size_t ix = (size_t)row * N + col;
        float v = acc[m][n][r];
        if (EPI == 0)      ((float*)Cout)[ix] = v;
        else if (EPI == 1) ((float*)Cout)[ix] = v + R[ix];
        else               ((bf16*)Cout)[ix] = (bf16)v;
      }
}

// ---------------- 256x256 8-phase GEMM (big-N shapes; M=2048 fixed) ----------------
// 512 thr / 8 waves (2Mx4N), BK=64 split kc-half-major in LDS:
//   A slab(buf,kc) = [256 rows][32 cols] bf16, row stride 64B -> bank-uniform ds_read_b128
//   double-buffered, staged via global_load_lds (linear dest), counted vmcnt(4),
//   raw s_barrier, setprio around each 16-MFMA cluster, bijective XCD swizzle.
template <int EPI>
__global__ __launch_bounds__(512, 2) void gemm8_bt(const bf16* __restrict__ A,
                                                   const bf16* __restrict__ BT,
                                                   void* __restrict__ Cout,
                                                   const float* __restrict__ R,
                                                   int N, int K) {
  extern __shared__ char smem[];   // 131072 B: A [0,65536), B [65536,131072)
  const int t = threadIdx.x;
  const int wid = t >> 6, l = t & 63;
  const int l15 = l & 15, l4 = l >> 4;
  const int wr = wid >> 2, wc = wid & 3;

  int nwg = gridDim.x;
  int q = nwg >> 3, r = nwg & 7;
  int xcd = blockIdx.x & 7, jj = blockIdx.x >> 3;
  int L = (xcd < r ? xcd * (q + 1) : r * (q + 1) + (xcd - r) * q) + jj;
  const int bm = (L & 7) * 256, bn = (L >> 3) * 256;

  const int NT = K >> 6;

  auto stage = [&](const bf16* __restrict__ G, int rowbase, int cbase, int buf, int kc, int kt) {
#pragma unroll
    for (int i = 0; i < 2; ++i) {
      int j = i * 512 + t;
      const bf16* src = G + (size_t)(rowbase + (j >> 2)) * K + kt * 64 + kc * 32 + (j & 3) * 8;
      __builtin_amdgcn_global_load_lds(
          (const __attribute__((address_space(1))) void*)src,
          (__attribute__((address_space(3))) void*)(smem + cbase + buf * 32768 + kc * 16384 +
                                                    i * 8192 + wid * 1024),
          16, 0, 0);
    }
  };
  auto ldA = [&](int buf, int kc, int m) -> bf16x8 {
    return *(const bf16x8*)(smem + buf * 32768 + kc * 16384 +
                            (wr * 128 + m * 16 + l15) * 64 + l4 * 16);
  };
  auto ldB = [&](int buf, int kc, int n) -> bf16x8 {
    return *(const bf16x8*)(smem + 65536 + buf * 32768 + kc * 16384 +
                            (wc * 64 + n * 16 + l15) * 64 + l4 * 16);
  };

  f32x4 acc[8][4] = {};

  // prologue: stage tile 0 (both kc halves), wait for kc0 pair
  stage(A, bm, 0, 0, 0, 0);
  stage(BT, bn, 65536, 0, 0, 0);
  stage(A, bm, 0, 0, 1, 0);
  stage(BT, bn, 65536, 0, 1, 0);
  asm volatile("s_waitcnt vmcnt(4)" ::: "memory");
  __builtin_amdgcn_sched_barrier(0);
  __builtin_amdgcn_s_barrier();

  for (int kt = 0; kt < NT; ++kt) {
    const int buf = kt & 1, nbuf = buf ^ 1;
    const bool more = (kt + 1 < NT);
    bf16x8 af[4], bq[4];

    // ---- ph1: kc0, m0-3 ----
#pragma unroll
    for (int m = 0; m < 4; ++m) af[m] = ldA(buf, 0, m);
#pragma unroll
    for (int n = 0; n < 4; ++n) bq[n] = ldB(buf, 0, n);
    if (more) stage(A, bm, 0, nbuf, 0, kt + 1);
    __builtin_amdgcn_sched_barrier(0);
    __builtin_amdgcn_s_barrier();
    __builtin_amdgcn_s_setprio(1);
#pragma unroll
    for (int m = 0; m < 4; ++m)
#pragma unroll
      for (int n = 0; n < 4; ++n)
        acc[m][n] = __builtin_amdgcn_mfma_f32_16x16x32_bf16(af[m], bq[n], acc[m][n], 0, 0, 0);
    __builtin_amdgcn_s_setprio(0);
    __builtin_amdgcn_sched_barrier(0);
    __builtin_amdgcn_s_barrier();

    // ---- ph2: kc0, m4-7 ----
#pragma unroll
    for (int m = 0; m < 4; ++m) af[m] = ldA(buf, 0, 4 + m);
    if (more) {
      stage(BT, bn, 65536, nbuf, 0, kt + 1);
      asm volatile("s_waitcnt vmcnt(4)" ::: "memory");
    } else {
      asm volatile("s_waitcnt vmcnt(0)" ::: "memory");
    }
    __builtin_amdgcn_sched_barrier(0);
    __builtin_amdgcn_s_barrier();
    __builtin_amdgcn_s_setprio(1);
#pragma unroll
    for (int m = 0; m < 4; ++m)
#pragma unroll
      for (int n = 0; n < 4; ++n)
        acc[4 + m][n] = __builtin_amdgcn_mfma_f32_16x16x32_bf16(af[m], bq[n], acc[4 + m][n], 0, 0, 0);
    __builtin_amdgcn_s_setprio(0);
    __builtin_amdgcn_sched_barrier(0);
    __builtin_amdgcn_s_barrier();

    // ---- ph3: kc1, m0-3 ----
#pragma unroll
    for (int m = 0; m < 4; ++m) af[m] = ldA(buf, 1, m);
#pragma unroll
    for (int n = 0; n < 4; ++n) bq[n] = ldB(buf, 1, n);
    if (more) stage(A, bm, 0, nbuf, 1, kt + 1);
    __builtin_amdgcn_sched_barrier(0);
    __builtin_amdgcn_s_barrier();
    __builtin_amdgcn_s_setprio(1);
#pragma unroll
    for (int m = 0; m < 4; ++m)
#pragma unroll
      for (int n = 0; n < 4; ++n)
        acc[m][n] = __builtin_amdgcn_mfma_f32_16x16x32_bf16(af[m], bq[n], acc[m][n], 0, 0, 0);
    __builtin_amdgcn_s_setprio(0);
    __builtin_amdgcn_sched_barrier(0);
    __builtin_amdgcn_s_barrier();

    // ---- ph4: kc1, m4-7 ----
#pragma unroll
    for (int m = 0; m < 4; ++m) af[m] = ldA(buf, 1, 4 + m);
    if (more) {
      stage(BT, bn, 65536, nbuf, 1, kt + 1);
      asm volatile("s_waitcnt vmcnt(4)" ::: "memory");
    }
    __builtin_amdgcn_sched_barrier(0);
    __builtin_amdgcn_s_barrier();
    __builtin_amdgcn_s_setprio(1);
#pragma unroll
    for (int m = 0; m < 4; ++m)
#pragma unroll
      for (int n = 0; n < 4; ++n)
        acc[4 + m][n] = __builtin_amdgcn_mfma_f32_16x16x32_bf16(af[m], bq[n], acc[4 + m][n], 0, 0, 0);
    __builtin_amdgcn_s_setprio(0);
    __builtin_amdgcn_sched_barrier(0);
    __builtin_amdgcn_s_barrier();
  }

#pragma unroll
  for (int m = 0; m < 8; ++m)
#pragma unroll
    for (int n = 0; n < 4; ++n)
#pragma unroll
      for (int rr = 0; rr < 4; ++rr) {
        int row = bm + wr * 128 + m * 16 + l4 * 4 + rr;
        int col = bn + wc * 64 + n * 16 + l15;
        size_t ix = (size_t)row * N + col;
        float v = acc[m][n][rr];
        if (EPI == 0)      ((float*)Cout)[ix] = v;
        else if (EPI == 1) ((float*)Cout)[ix] = v + R[ix];
        else               ((bf16*)Cout)[ix] = (bf16)v;
      }
}

// ---------------- rope on q ----------------
__global__ __launch_bounds__(256) void rope_q_k(const bf16* __restrict__ qkv,
                                                const float* __restrict__ tab,
                                                bf16* __restrict__ q_r) {
  int i = blockIdx.x * 256 + threadIdx.x;
  int d = i & 31, h = (i >> 5) & 15, s = (i >> 9) & 1023, b = i >> 19;
  size_t src = (size_t)(b * S_ + s) * 1536 + h * 64 + 2 * d;
  float a  = (float)qkv[src];
  float bb = (float)qkv[src + 1];
  float c  = tab[(s * 32 + d) * 2];
  float sn = tab[(s * 32 + d) * 2 + 1];
  size_t o = ((size_t)((b * HQ_ + h) * S_ + s)) * 64 + 2 * d;
  q_r[o]     = (bf16)(a * c - bb * sn);
  q_r[o + 1] = (bf16)(a * sn + bb * c);
}

// ---------------- rope on k ----------------
__global__ __launch_bounds__(256) void rope_k_k(const bf16* __restrict__ qkv,
                                                const float* __restrict__ tab,
                                                bf16* __restrict__ k_r) {
  int i = blockIdx.x * 256 + threadIdx.x;
  int d = i & 31, h = (i >> 5) & 3, s = (i >> 7) & 1023, b = i >> 17;
  size_t src = (size_t)(b * S_ + s) * 1536 + 1024 + h * 64 + 2 * d;
  float a  = (float)qkv[src];
  float bb = (float)qkv[src + 1];
  float c  = tab[(s * 32 + d) * 2];
  float sn = tab[(s * 32 + d) * 2 + 1];
  size_t o = ((size_t)((b * HK_ + h) * S_ + s)) * 64 + 2 * d;
  k_r[o]     = (bf16)(a * c - bb * sn);
  k_r[o + 1] = (bf16)(a * sn + bb * c);
}

// ---------------- v transpose ----------------
__global__ __launch_bounds__(256) void vtr_k(const bf16* __restrict__ qkv,
                                             bf16* __restrict__ vT) {
  int i = blockIdx.x * 256 + threadIdx.x;
  int s = i & 1023, dh = (i >> 10) & 63, h = (i >> 16) & 3, b = i >> 18;
  vT[((size_t)((b * HK_ + h) * 64 + dh)) * S_ + s] =
      qkv[(size_t)(b * S_ + s) * 1536 + 1280 + h * 64 + dh];
}

// ---------------- flash attention (causal, GQA) ----------------
__global__ __launch_bounds__(256) void attn_k(const bf16* __restrict__ q_r,
                                              const bf16* __restrict__ k_r,
                                              const bf16* __restrict__ vT,
                                              bf16* __restrict__ o) {
  __shared__ bf16 k_lds[64 * 64];
  __shared__ bf16 v_lds[64 * 64];
  __shared__ bf16 p_lds[4][16 * 72];
  int t = threadIdx.x, w = t >> 6, l = t & 63, l15 = l & 15, l4 = l >> 4;
  int qt = blockIdx.x & 15, head = (blockIdx.x >> 4) & 15, b = blockIdx.x >> 8;
  int kvh = head >> 2;
  const bf16* qh = q_r + ((size_t)(b * HQ_ + head)) * S_ * 64;
  const bf16* kh = k_r + ((size_t)(b * HK_ + kvh)) * S_ * 64;
  const bf16* vh = vT + ((size_t)(b * HK_ + kvh)) * 64 * S_;
  int q0 = qt * 64 + w * 16;

  bf16x8 aq[2];
  aq[0] = *(const bf16x8*)&qh[(size_t)(q0 + l15) * 64 + l4 * 8];
  aq[1] = *(const bf16x8*)&qh[(size_t)(q0 + l15) * 64 + 32 + l4 * 8];

  f32x4 acc_o[4] = {};
  float m_run[4], l_run[4];
#pragma unroll
  for (int r = 0; r < 4; ++r) { m_run[r] = -1e30f; l_run[r] = 0.f; }

  for (int kt = 0; kt <= qt; ++kt) {
    {
      const bf16* src = kh + kt * 4096;
#pragma unroll
      for (int i = 0; i < 2; ++i) {
        int c = i * 256 + t;
        *(bf16x8*)&k_lds[c * 8] = *(const bf16x8*)&src[c * 8];
      }
#pragma unroll
      for (int i = 0; i < 2; ++i) {
        int c = i * 256 + t;
        int row = c >> 3, col8 = (c & 7) * 8;
        *(bf16x8*)&v_lds[row * 64 + col8] = *(const bf16x8*)&vh[(size_t)row * S_ + kt * 64 + col8];
      }
    }
    __syncthreads();

    f32x4 sc[4];
#pragma unroll
    for (int nt = 0; nt < 4; ++nt) {
      f32x4 a = {};
#pragma unroll
      for (int kc = 0; kc < 2; ++kc) {
        bf16x8 bk = *(const bf16x8*)&k_lds[(nt * 16 + l15) * 64 + kc * 32 + l4 * 8];
        a = __builtin_amdgcn_mfma_f32_16x16x32_bf16(aq[kc], bk, a, 0, 0, 0);
      }
      sc[nt] = a;
    }

    bool diag = (kt == qt);
#pragma unroll
    for (int r = 0; r < 4; ++r) {
      float mx = -1e30f;
#pragma unroll
      for (int nt = 0; nt < 4; ++nt) {
        float s = sc[nt][r] * 0.125f;
        if (diag) {
          int kj = nt * 16 + l15;
          int qi = w * 16 + l4 * 4 + r;
          if (kj > qi) s = -1e30f;
        }
        sc[nt][r] = s;
        mx = fmaxf(mx, s);
      }
      mx = fmaxf(mx, __shfl_xor(mx, 1, 64));
      mx = fmaxf(mx, __shfl_xor(mx, 2, 64));
      mx = fmaxf(mx, __shfl_xor(mx, 4, 64));
      mx = fmaxf(mx, __shfl_xor(mx, 8, 64));
      float mn = fmaxf(m_run[r], mx);
      float scale = __expf(m_run[r] - mn);
      m_run[r] = mn;
      float rs = 0.f;
#pragma unroll
      for (int nt = 0; nt < 4; ++nt) {
        float p = __expf(sc[nt][r] - mn);
        sc[nt][r] = p;
        rs += p;
      }
      rs += __shfl_xor(rs, 1, 64);
      rs += __shfl_xor(rs, 2, 64);
      rs += __shfl_xor(rs, 4, 64);
      rs += __shfl_xor(rs, 8, 64);
      l_run[r] = l_run[r] * scale + rs;
#pragma unroll
      for (int nt = 0; nt < 4; ++nt) acc_o[nt][r] *= scale;
    }

#pragma unroll
    for (int nt = 0; nt < 4; ++nt)
#pragma unroll
      for (int r = 0; r < 4; ++r)
        p_lds[w][(l4 * 4 + r) * 72 + nt * 16 + l15] = (bf16)sc[nt][r];
    asm volatile("s_waitcnt lgkmcnt(0)" ::: "memory");
    __builtin_amdgcn_sched_barrier(0);

#pragma unroll
    for (int kc = 0; kc < 2; ++kc) {
      bf16x8 pf = *(const bf16x8*)&p_lds[w][l15 * 72 + kc * 32 + l4 * 8];
#pragma unroll
      for (int nt = 0; nt < 4; ++nt) {
        bf16x8 vf = *(const bf16x8*)&v_lds[(nt * 16 + l15) * 64 + kc * 32 + l4 * 8];
        acc_o[nt] = __builtin_amdgcn_mfma_f32_16x16x32_bf16(pf, vf, acc_o[nt], 0, 0, 0);
      }
    }
    __syncthreads();
  }

#pragma unroll
  for (int nt = 0; nt < 4; ++nt)
#pragma unroll
    for (int r = 0; r < 4; ++r) {
      float ov = acc_o[nt][r] / l_run[r];
      int s = qt * 64 + w * 16 + l4 * 4 + r;
      o[((size_t)(b * S_ + s)) * D_ + head * 64 + nt * 16 + l15] = (bf16)ov;
    }
}

// ---------------- silu(ff1) * ff3 -> gate bf16 ----------------
__global__ __launch_bounds__(256) void silumul_k(const bf16* __restrict__ ff,
                                                 bf16* __restrict__ gate) {
  int p = blockIdx.x * 256 + threadIdx.x;
  int row = p / 352;
  int j = (p % 352) * 8;
  bf16x8 a = *(const bf16x8*)&ff[(size_t)row * 5632 + j];
  bf16x8 c = *(const bf16x8*)&ff[(size_t)row * 5632 + 2816 + j];
  bf16x8 g;
#pragma unroll
  for (int i = 0; i < 8; ++i) {
    float x = (float)a[i];
    float s = x / (1.0f + __expf(-x));
    g[i] = (bf16)(s * (float)c[i]);
  }
  *(bf16x8*)&gate[(size_t)row * 2816 + j] = g;
}

// =======================================================================
extern "C" void kernel_launch(void* const* d_in, const int* in_sizes, int n_in,
                              void* d_out, int out_size, void* d_ws, size_t ws_size,
                              hipStream_t stream) {
  const int* tokens  = (const int*)d_in[0];
  const float* tok_emb = (const float*)d_in[2];
  const float* wq = (const float*)d_in[3];
  const float* wk = (const float*)d_in[4];
  const float* wv = (const float*)d_in[5];
  const float* wo = (const float*)d_in[6];
  const float* w1 = (const float*)d_in[7];
  const float* w2 = (const float*)d_in[8];
  const float* w3 = (const float*)d_in[9];
  const float* anw = (const float*)d_in[10];
  const float* fnw = (const float*)d_in[11];
  const float* finw = (const float*)d_in[12];
  const float* outw = (const float*)d_in[13];

  (void)hipFuncSetAttribute((const void*)gemm8_bt<0>,
                            hipFuncAttributeMaxDynamicSharedMemorySize, 131072);
  (void)hipFuncSetAttribute((const void*)gemm8_bt<2>,
                            hipFuncAttributeMaxDynamicSharedMemorySize, 131072);

  auto al = [](size_t x) { return (x + 255) & ~(size_t)255; };
  const size_t WTB   = 11272192ull * 2;
  const size_t OUTWTB = (size_t)V_ * D_ * 2;
  const size_t HB   = (size_t)B_ * S_ * D_ * 4;
  const size_t XBB  = (size_t)B_ * S_ * D_ * 2;
  const size_t QKVB = (size_t)B_ * S_ * 1536 * 2;
  const size_t QRB  = (size_t)B_ * HQ_ * S_ * 64 * 2;
  const size_t KRB  = (size_t)B_ * HK_ * S_ * 64 * 2;
  const size_t OB   = (size_t)B_ * S_ * D_ * 2;
  const size_t FFB  = (size_t)B_ * S_ * 5632 * 2;
  const size_t GATEB = (size_t)B_ * S_ * 2816 * 2;
  const size_t TABB = (size_t)S_ * 32 * 2 * 4;

  size_t fixed = al(OUTWTB) + al(HB) + al(XBB) + al(QKVB) + al(QRB) + al(KRB) + al(KRB) +
                 al(OB) + al(FFB) + al(GATEB) + al(TABB);
  bool allup = ws_size >= fixed + 8 * al(WTB) + 4096;
  int nslots = allup ? 8 : 1;

  char* p = (char*)d_ws;
  bf16* wT    = (bf16*)p; p += (size_t)nslots * al(WTB);
  bf16* outwT = (bf16*)p; p += al(OUTWTB);
  float* h    = (float*)p; p += al(HB);
  bf16* xb    = (bf16*)p; p += al(XBB);
  bf16* qkv   = (bf16*)p; p += al(QKVB);
  bf16* q_r   = (bf16*)p; p += al(QRB);
  bf16* k_r   = (bf16*)p; p += al(KRB);
  bf16* vTb   = (bf16*)p; p += al(KRB);
  bf16* ob    = (bf16*)p; p += al(OB);
  bf16* ff    = (bf16*)p; p += al(FFB);
  bf16* gate  = (bf16*)p; p += al(GATEB);
  float* tab  = (float*)p; p += al(TABB);

  const size_t WTS = al(WTB) / 2;
  const size_t OFF_QKV = 0;
  const size_t OFF_WK  = 1024ull * 1024;
  const size_t OFF_WV  = 1280ull * 1024;
  const size_t OFF_WO  = 1572864ull;
  const size_t OFF_W13 = 2621440ull;
  const size_t OFF_W3  = 2621440ull + 2816ull * 1024;
  const size_t OFF_W2  = 8388608ull;

  auto tr = [&](const float* src, size_t srcStride, bf16* dst, size_t dstStride,
                int Kd, int Nd, int layers) {
    transpose_cvt<<<dim3(Nd / 32, Kd / 32, layers), 256, 0, stream>>>(
        src, dst, Kd, Nd, (long long)srcStride, (long long)dstStride);
  };

  ropetab_k<<<128, 256, 0, stream>>>(tab);
  embed_k<<<B_ * S_, 256, 0, stream>>>(tokens, tok_emb, h);
  tr(outw, 0, outwT, 0, 1024, 32000, 1);

  if (allup) {
    tr(wq, 1024 * 1024, wT + OFF_QKV, WTS, 1024, 1024, 8);
    tr(wk, 1024 * 256,  wT + OFF_WK,  WTS, 1024, 256, 8);
    tr(wv, 1024 * 256,  wT + OFF_WV,  WTS, 1024, 256, 8);
    tr(wo, 1024 * 1024, wT + OFF_WO,  WTS, 1024, 1024, 8);
    tr(w1, 1024 * 2816, wT + OFF_W13, WTS, 1024, 2816, 8);
    tr(w3, 1024 * 2816, wT + OFF_W3,  WTS, 1024, 2816, 8);
    tr(w2, 2816 * 1024, wT + OFF_W2,  WTS, 2816, 1024, 8);
  }

  for (int l = 0; l < L_; ++l) {
    bf16* wtl = wT + (allup ? (size_t)l * WTS : 0);
    if (!allup) {
      tr(wq + (size_t)l * 1024 * 1024, 0, wtl + OFF_QKV, 0, 1024, 1024, 1);
      tr(wk + (size_t)l * 1024 * 256,  0, wtl + OFF_WK,  0, 1024, 256, 1);
      tr(wv + (size_t)l * 1024 * 256,  0, wtl + OFF_WV,  0, 1024, 256, 1);
      tr(wo + (size_t)l * 1024 * 1024, 0, wtl + OFF_WO,  0, 1024, 1024, 1);
      tr(w1 + (size_t)l * 1024 * 2816, 0, wtl + OFF_W13, 0, 1024, 2816, 1);
      tr(w3 + (size_t)l * 1024 * 2816, 0, wtl + OFF_W3,  0, 1024, 2816, 1);
      tr(w2 + (size_t)l * 2816 * 1024, 0, wtl + OFF_W2,  0, 2816, 1024, 1);
    }

    rmsnorm_k<<<B_ * S_, 256, 0, stream>>>(h, anw + l * D_, xb);
    gemm_bt<2><<<dim3(16, 12), 256, 0, stream>>>(xb, wtl + OFF_QKV, qkv, nullptr, 2048, 1536, 1024);
    rope_q_k<<<4096, 256, 0, stream>>>(qkv, tab, q_r);
    rope_k_k<<<1024, 256, 0, stream>>>(qkv, tab, k_r);
    vtr_k<<<2048, 256, 0, stream>>>(qkv, vTb);
    attn_k<<<B_ * HQ_ * (S_ / 64), 256, 0, stream>>>(q_r, k_r, vTb, ob);
    gemm_bt<1><<<dim3(16, 8), 256, 0, stream>>>(ob, wtl + OFF_WO, h, h, 2048, 1024, 1024);
    rmsnorm_k<<<B_ * S_, 256, 0, stream>>>(h, fnw + l * D_, xb);
    gemm8_bt<2><<<176, 512, 131072, stream>>>(xb, wtl + OFF_W13, ff, nullptr, 5632, 1024);
    silumul_k<<<2816, 256, 0, stream>>>(ff, gate);
    gemm_bt<1><<<dim3(16, 8), 256, 0, stream>>>(gate, wtl + OFF_W2, h, h, 2048, 1024, 2816);
  }

  rmsnorm_k<<<B_ * S_, 256, 0, stream>>>(h, finw, xb);
  gemm8_bt<0><<<1000, 512, 131072, stream>>>(xb, outwT, d_out, nullptr, 32000, 1024);
}

// Round 4
// 2035.405 us; speedup vs baseline: 1.1305x; 1.0195x over previous
//
#include <hip/hip_runtime.h>
#include <hip/hip_bf16.h>

typedef __bf16 bf16;
typedef __bf16 bf16x8 __attribute__((ext_vector_type(8)));
typedef float f32x4 __attribute__((ext_vector_type(4)));

#define B_ 2
#define S_ 1024
#define D_ 1024
#define L_ 8
#define HQ_ 16
#define HK_ 4
#define DH_ 64
#define FF_ 2816
#define V_ 32000

// ---------------- embedding gather ----------------
__global__ __launch_bounds__(256) void embed_k(const int* __restrict__ toks,
                                               const float* __restrict__ emb,
                                               float* __restrict__ h) {
  int row = blockIdx.x;
  int tok = toks[row];
  f32x4 v = *(const f32x4*)&emb[(size_t)tok * D_ + threadIdx.x * 4];
  *(f32x4*)&h[(size_t)row * D_ + threadIdx.x * 4] = v;
}

// ---------------- rope table: tab[s][d] = {cos, sin} ----------------
__global__ __launch_bounds__(256) void ropetab_k(float* __restrict__ tab) {
  int i = blockIdx.x * 256 + threadIdx.x;
  if (i >= S_ * 32) return;
  int d = i & 31, s = i >> 5;
  float f = expf(-(2.0f * d / 64.0f) * logf(500000.0f));
  float ang = (float)s * f;
  tab[i * 2]     = cosf(ang);
  tab[i * 2 + 1] = sinf(ang);
}

// ---------------- rmsnorm: fp32 in -> bf16 out ----------------
__global__ __launch_bounds__(256) void rmsnorm_k(const float* __restrict__ x,
                                                 const float* __restrict__ w,
                                                 bf16* __restrict__ out) {
  int row = blockIdx.x;
  const float* xr = x + (size_t)row * D_;
  int base = threadIdx.x * 4;
  f32x4 v = *(const f32x4*)&xr[base];
  float ss = v[0]*v[0] + v[1]*v[1] + v[2]*v[2] + v[3]*v[3];
  for (int m = 1; m < 64; m <<= 1) ss += __shfl_xor(ss, m, 64);
  __shared__ float partial[4];
  if ((threadIdx.x & 63) == 0) partial[threadIdx.x >> 6] = ss;
  __syncthreads();
  float tot = partial[0] + partial[1] + partial[2] + partial[3];
  float rr = rsqrtf(tot * (1.0f / D_) + 1e-5f);
  f32x4 wv = *(const f32x4*)&w[base];
  bf16* o = out + (size_t)row * D_ + base;
  o[0] = (bf16)(v[0] * rr * wv[0]);
  o[1] = (bf16)(v[1] * rr * wv[1]);
  o[2] = (bf16)(v[2] * rr * wv[2]);
  o[3] = (bf16)(v[3] * rr * wv[3]);
}

// ---------------- transpose + fp32->bf16:  src[K][N] -> dst[N*rowMul+rowAdd][K] ----------------
__global__ __launch_bounds__(256) void transpose_cvt(const float* __restrict__ src,
                                                     bf16* __restrict__ dst,
                                                     int K, int N,
                                                     long long srcStride, long long dstStride,
                                                     int rowMul, int rowAdd) {
  __shared__ float tile[32][33];
  int bx = blockIdx.x, by = blockIdx.y, z = blockIdx.z;
  src += (size_t)z * srcStride;
  dst += (size_t)z * dstStride;
  int tx = threadIdx.x & 31, ty = threadIdx.x >> 5;
#pragma unroll
  for (int i = 0; i < 4; ++i) {
    int r = ty + i * 8;
    tile[r][tx] = src[(size_t)(by * 32 + r) * N + bx * 32 + tx];
  }
  __syncthreads();
#pragma unroll
  for (int i = 0; i < 4; ++i) {
    int r = ty + i * 8;
    dst[(size_t)((bx * 32 + r) * rowMul + rowAdd) * K + by * 32 + tx] = (bf16)tile[tx][r];
  }
}

// ---------------- 128x128 2-phase GEMM (small-N shapes) ----------------
// EPI 0: fp32 out.  EPI 1: fp32 out = acc + R.  EPI 2: bf16 out.
template <int EPI>
__global__ __launch_bounds__(256) void gemm_bt(const bf16* __restrict__ A,
                                               const bf16* __restrict__ BT,
                                               void* __restrict__ Cout,
                                               const float* __restrict__ R,
                                               int M, int N, int K) {
  __shared__ bf16 As[128 * 64];
  __shared__ bf16 Bs[128 * 64];
  const int t = threadIdx.x;
  const int w = t >> 6, l = t & 63;
  const int l15 = l & 15, l4 = l >> 4;
  const int bm = blockIdx.x * 128, bn = blockIdx.y * 128;
  const int wr = w >> 1, wc = w & 1;

  const int srow = t >> 3, scol = (t & 7) * 8;
  const bf16* ag = &A[(size_t)(bm + srow) * K + scol];
  const bf16* bg = &BT[(size_t)(bn + srow) * K + scol];
  const int ldsbase = (t & 192) * 8;

  f32x4 acc[4][4] = {};

  for (int k0 = 0; k0 < K; k0 += 64) {
#pragma unroll
    for (int i = 0; i < 4; ++i) {
      __builtin_amdgcn_global_load_lds(
          (const __attribute__((address_space(1))) void*)(ag + (size_t)(i * 32) * K + k0),
          (__attribute__((address_space(3))) void*)&As[i * 2048 + ldsbase], 16, 0, 0);
      __builtin_amdgcn_global_load_lds(
          (const __attribute__((address_space(1))) void*)(bg + (size_t)(i * 32) * K + k0),
          (__attribute__((address_space(3))) void*)&Bs[i * 2048 + ldsbase], 16, 0, 0);
    }
    __syncthreads();
#pragma unroll
    for (int kc = 0; kc < 2; ++kc) {
      bf16x8 af[4], bfr[4];
#pragma unroll
      for (int m = 0; m < 4; ++m)
        af[m] = *(const bf16x8*)&As[(wr * 64 + m * 16 + l15) * 64 + kc * 32 + l4 * 8];
#pragma unroll
      for (int n = 0; n < 4; ++n)
        bfr[n] = *(const bf16x8*)&Bs[(wc * 64 + n * 16 + l15) * 64 + kc * 32 + l4 * 8];
#pragma unroll
      for (int m = 0; m < 4; ++m)
#pragma unroll
        for (int n = 0; n < 4; ++n)
          acc[m][n] = __builtin_amdgcn_mfma_f32_16x16x32_bf16(af[m], bfr[n], acc[m][n], 0, 0, 0);
    }
    __syncthreads();
  }

#pragma unroll
  for (int m = 0; m < 4; ++m)
#pragma unroll
    for (int n = 0; n < 4; ++n)
#pragma unroll
      for (int r = 0; r < 4; ++r) {
        int row = bm + wr * 64 + m * 16 + l4 * 4 + r;
        int col = bn + wc * 64 + n * 16 + l15;
        size_t ix = (size_t)row * N + col;
        float v = acc[m][n][r];
        if (EPI == 0)      ((float*)Cout)[ix] = v;
        else if (EPI == 1) ((float*)Cout)[ix] = v + R[ix];
        else               ((bf16*)Cout)[ix] = (bf16)v;
      }
}

// ---------------- 256x256 8-phase GEMM (big-N shapes; M=2048 fixed) ----------------
// kc-half-major LDS slabs [256 rows][32 cols], row stride 64B, with chunk-XOR swizzle
// chunk' = chunk ^ ((row>>1)&3) applied as pre-swizzled GLOBAL source (linear LDS dest,
// rule #21) + swizzled ds_read -> 2-way banks (free).  Double-buffered, counted vmcnt(4),
// setprio MFMA clusters, bijective XCD swizzle.
// EPI 0: fp32 out.  EPI 3: interleaved-w13 fused silu: cols even=w1,odd=w3;
//        gate[row][col>>1] = silu(a)*c  (bf16, N_gate = N/2).
template <int EPI>
__global__ __launch_bounds__(512, 2) void gemm8_bt(const bf16* __restrict__ A,
                                                   const bf16* __restrict__ BT,
                                                   void* __restrict__ Cout,
                                                   const float* __restrict__ R,
                                                   int N, int K) {
  extern __shared__ char smem[];   // 131072 B: A [0,65536), B [65536,131072)
  const int t = threadIdx.x;
  const int wid = t >> 6, l = t & 63;
  const int l15 = l & 15, l4 = l >> 4;
  const int wr = wid >> 2, wc = wid & 3;
  // read-side swizzled chunk offset (bytes): chunk l4 of row (..+l15) lives at l4^((l15>>1)&3)
  const int rsw = (l4 ^ ((l15 >> 1) & 3)) * 16;
  // stage-side: thread t stages LDS chunk (t&3) of row (t>>2); source col chunk is XOR'd
  const int csw = ((t & 3) ^ ((t >> 3) & 3)) * 8;   // elems

  int nwg = gridDim.x;
  int q = nwg >> 3, r = nwg & 7;
  int xcd = blockIdx.x & 7, jj = blockIdx.x >> 3;
  int L = (xcd < r ? xcd * (q + 1) : r * (q + 1) + (xcd - r) * q) + jj;
  const int bm = (L & 7) * 256, bn = (L >> 3) * 256;

  const int NT = K >> 6;

  auto stage = [&](const bf16* __restrict__ G, int rowbase, int cbase, int buf, int kc, int kt) {
#pragma unroll
    for (int i = 0; i < 2; ++i) {
      int j = i * 512 + t;
      const bf16* src = G + (size_t)(rowbase + (j >> 2)) * K + kt * 64 + kc * 32 + csw;
      __builtin_amdgcn_global_load_lds(
          (const __attribute__((address_space(1))) void*)src,
          (__attribute__((address_space(3))) void*)(smem + cbase + buf * 32768 + kc * 16384 +
                                                    i * 8192 + wid * 1024),
          16, 0, 0);
    }
  };
  auto ldA = [&](int buf, int kc, int m) -> bf16x8 {
    return *(const bf16x8*)(smem + buf * 32768 + kc * 16384 +
                            (wr * 128 + m * 16 + l15) * 64 + rsw);
  };
  auto ldB = [&](int buf, int kc, int n) -> bf16x8 {
    return *(const bf16x8*)(smem + 65536 + buf * 32768 + kc * 16384 +
                            (wc * 64 + n * 16 + l15) * 64 + rsw);
  };

  f32x4 acc[8][4] = {};

  stage(A, bm, 0, 0, 0, 0);
  stage(BT, bn, 65536, 0, 0, 0);
  stage(A, bm, 0, 0, 1, 0);
  stage(BT, bn, 65536, 0, 1, 0);
  asm volatile("s_waitcnt vmcnt(4)" ::: "memory");
  __builtin_amdgcn_sched_barrier(0);
  __builtin_amdgcn_s_barrier();

  for (int kt = 0; kt < NT; ++kt) {
    const int buf = kt & 1, nbuf = buf ^ 1;
    const bool more = (kt + 1 < NT);
    bf16x8 af[4], bq[4];

    // ---- ph1: kc0, m0-3 ----
#pragma unroll
    for (int m = 0; m < 4; ++m) af[m] = ldA(buf, 0, m);
#pragma unroll
    for (int n = 0; n < 4; ++n) bq[n] = ldB(buf, 0, n);
    if (more) stage(A, bm, 0, nbuf, 0, kt + 1);
    __builtin_amdgcn_sched_barrier(0);
    __builtin_amdgcn_s_barrier();
    __builtin_amdgcn_s_setprio(1);
#pragma unroll
    for (int m = 0; m < 4; ++m)
#pragma unroll
      for (int n = 0; n < 4; ++n)
        acc[m][n] = __builtin_amdgcn_mfma_f32_16x16x32_bf16(af[m], bq[n], acc[m][n], 0, 0, 0);
    __builtin_amdgcn_s_setprio(0);
    __builtin_amdgcn_sched_barrier(0);
    __builtin_amdgcn_s_barrier();

    // ---- ph2: kc0, m4-7 ----
#pragma unroll
    for (int m = 0; m < 4; ++m) af[m] = ldA(buf, 0, 4 + m);
    if (more) {
      stage(BT, bn, 65536, nbuf, 0, kt + 1);
      asm volatile("s_waitcnt vmcnt(4)" ::: "memory");
    } else {
      asm volatile("s_waitcnt vmcnt(0)" ::: "memory");
    }
    __builtin_amdgcn_sched_barrier(0);
    __builtin_amdgcn_s_barrier();
    __builtin_amdgcn_s_setprio(1);
#pragma unroll
    for (int m = 0; m < 4; ++m)
#pragma unroll
      for (int n = 0; n < 4; ++n)
        acc[4 + m][n] = __builtin_amdgcn_mfma_f32_16x16x32_bf16(af[m], bq[n], acc[4 + m][n], 0, 0, 0);
    __builtin_amdgcn_s_setprio(0);
    __builtin_amdgcn_sched_barrier(0);
    __builtin_amdgcn_s_barrier();

    // ---- ph3: kc1, m0-3 ----
#pragma unroll
    for (int m = 0; m < 4; ++m) af[m] = ldA(buf, 1, m);
#pragma unroll
    for (int n = 0; n < 4; ++n) bq[n] = ldB(buf, 1, n);
    if (more) stage(A, bm, 0, nbuf, 1, kt + 1);
    __builtin_amdgcn_sched_barrier(0);
    __builtin_amdgcn_s_barrier();
    __builtin_amdgcn_s_setprio(1);
#pragma unroll
    for (int m = 0; m < 4; ++m)
#pragma unroll
      for (int n = 0; n < 4; ++n)
        acc[m][n] = __builtin_amdgcn_mfma_f32_16x16x32_bf16(af[m], bq[n], acc[m][n], 0, 0, 0);
    __builtin_amdgcn_s_setprio(0);
    __builtin_amdgcn_sched_barrier(0);
    __builtin_amdgcn_s_barrier();

    // ---- ph4: kc1, m4-7 ----
#pragma unroll
    for (int m = 0; m < 4; ++m) af[m] = ldA(buf, 1, 4 + m);
    if (more) {
      stage(BT, bn, 65536, nbuf, 1, kt + 1);
      asm volatile("s_waitcnt vmcnt(4)" ::: "memory");
    }
    __builtin_amdgcn_sched_barrier(0);
    __builtin_amdgcn_s_barrier();
    __builtin_amdgcn_s_setprio(1);
#pragma unroll
    for (int m = 0; m < 4; ++m)
#pragma unroll
      for (int n = 0; n < 4; ++n)
        acc[4 + m][n] = __builtin_amdgcn_mfma_f32_16x16x32_bf16(af[m], bq[n], acc[4 + m][n], 0, 0, 0);
    __builtin_amdgcn_s_setprio(0);
    __builtin_amdgcn_sched_barrier(0);
    __builtin_amdgcn_s_barrier();
  }

  if (EPI == 3) {
    bf16* G = (bf16*)Cout;
    const int Nc = N >> 1;
#pragma unroll
    for (int m = 0; m < 8; ++m)
#pragma unroll
      for (int n = 0; n < 4; ++n)
#pragma unroll
        for (int rr = 0; rr < 4; ++rr) {
          float v = acc[m][n][rr];
          float part = __shfl_xor(v, 1, 64);
          if (!(l15 & 1)) {
            float a = v, c = part;
            float s = a / (1.0f + __expf(-a));
            int row = bm + wr * 128 + m * 16 + l4 * 4 + rr;
            int col = (bn >> 1) + wc * 32 + n * 8 + (l15 >> 1);
            G[(size_t)row * Nc + col] = (bf16)(s * c);
          }
        }
  } else {
#pragma unroll
    for (int m = 0; m < 8; ++m)
#pragma unroll
      for (int n = 0; n < 4; ++n)
#pragma unroll
        for (int rr = 0; rr < 4; ++rr) {
          int row = bm + wr * 128 + m * 16 + l4 * 4 + rr;
          int col = bn + wc * 64 + n * 16 + l15;
          size_t ix = (size_t)row * N + col;
          float v = acc[m][n][rr];
          if (EPI == 0)      ((float*)Cout)[ix] = v;
          else if (EPI == 1) ((float*)Cout)[ix] = v + R[ix];
          else               ((bf16*)Cout)[ix] = (bf16)v;
        }
  }
}

// ---------------- fused qkv post: rope(q), rope(k), transpose(v) ----------------
__global__ __launch_bounds__(256) void qkvpost_k(const bf16* __restrict__ qkv,
                                                 const float* __restrict__ tab,
                                                 bf16* __restrict__ q_r,
                                                 bf16* __restrict__ k_r,
                                                 bf16* __restrict__ vT) {
  int bid = blockIdx.x;
  if (bid < 4096) {                       // rope q: 2^20 pairs
    int i = bid * 256 + threadIdx.x;
    int d = i & 31, h = (i >> 5) & 15, s = (i >> 9) & 1023, b = i >> 19;
    size_t src = (size_t)(b * S_ + s) * 1536 + h * 64 + 2 * d;
    float a  = (float)qkv[src];
    float bb = (float)qkv[src + 1];
    float c  = tab[(s * 32 + d) * 2];
    float sn = tab[(s * 32 + d) * 2 + 1];
    size_t o = ((size_t)((b * HQ_ + h) * S_ + s)) * 64 + 2 * d;
    q_r[o]     = (bf16)(a * c - bb * sn);
    q_r[o + 1] = (bf16)(a * sn + bb * c);
  } else if (bid < 5120) {                // rope k: 2^18 pairs
    int i = (bid - 4096) * 256 + threadIdx.x;
    int d = i & 31, h = (i >> 5) & 3, s = (i >> 7) & 1023, b = i >> 17;
    size_t src = (size_t)(b * S_ + s) * 1536 + 1024 + h * 64 + 2 * d;
    float a  = (float)qkv[src];
    float bb = (float)qkv[src + 1];
    float c  = tab[(s * 32 + d) * 2];
    float sn = tab[(s * 32 + d) * 2 + 1];
    size_t o = ((size_t)((b * HK_ + h) * S_ + s)) * 64 + 2 * d;
    k_r[o]     = (bf16)(a * c - bb * sn);
    k_r[o + 1] = (bf16)(a * sn + bb * c);
  } else {                                // v transpose: 2^19 elems
    int i = (bid - 5120) * 256 + threadIdx.x;
    int s = i & 1023, dh = (i >> 10) & 63, h = (i >> 16) & 3, b = i >> 18;
    vT[((size_t)((b * HK_ + h) * 64 + dh)) * S_ + s] =
        qkv[(size_t)(b * S_ + s) * 1536 + 1280 + h * 64 + dh];
  }
}

// ---------------- flash attention (causal, GQA) ----------------
__global__ __launch_bounds__(256) void attn_k(const bf16* __restrict__ q_r,
                                              const bf16* __restrict__ k_r,
                                              const bf16* __restrict__ vT,
                                              bf16* __restrict__ o) {
  __shared__ bf16 k_lds[64 * 64];
  __shared__ bf16 v_lds[64 * 64];
  __shared__ bf16 p_lds[4][16 * 72];
  int t = threadIdx.x, w = t >> 6, l = t & 63, l15 = l & 15, l4 = l >> 4;
  int qt = blockIdx.x & 15, head = (blockIdx.x >> 4) & 15, b = blockIdx.x >> 8;
  int kvh = head >> 2;
  const bf16* qh = q_r + ((size_t)(b * HQ_ + head)) * S_ * 64;
  const bf16* kh = k_r + ((size_t)(b * HK_ + kvh)) * S_ * 64;
  const bf16* vh = vT + ((size_t)(b * HK_ + kvh)) * 64 * S_;
  int q0 = qt * 64 + w * 16;

  bf16x8 aq[2];
  aq[0] = *(const bf16x8*)&qh[(size_t)(q0 + l15) * 64 + l4 * 8];
  aq[1] = *(const bf16x8*)&qh[(size_t)(q0 + l15) * 64 + 32 + l4 * 8];

  f32x4 acc_o[4] = {};
  float m_run[4], l_run[4];
#pragma unroll
  for (int r = 0; r < 4; ++r) { m_run[r] = -1e30f; l_run[r] = 0.f; }

  for (int kt = 0; kt <= qt; ++kt) {
    {
      const bf16* src = kh + kt * 4096;
#pragma unroll
      for (int i = 0; i < 2; ++i) {
        int c = i * 256 + t;
        *(bf16x8*)&k_lds[c * 8] = *(const bf16x8*)&src[c * 8];
      }
#pragma unroll
      for (int i = 0; i < 2; ++i) {
        int c = i * 256 + t;
        int row = c >> 3, col8 = (c & 7) * 8;
        *(bf16x8*)&v_lds[row * 64 + col8] = *(const bf16x8*)&vh[(size_t)row * S_ + kt * 64 + col8];
      }
    }
    __syncthreads();

    f32x4 sc[4];
#pragma unroll
    for (int nt = 0; nt < 4; ++nt) {
      f32x4 a = {};
#pragma unroll
      for (int kc = 0; kc < 2; ++kc) {
        bf16x8 bk = *(const bf16x8*)&k_lds[(nt * 16 + l15) * 64 + kc * 32 + l4 * 8];
        a = __builtin_amdgcn_mfma_f32_16x16x32_bf16(aq[kc], bk, a, 0, 0, 0);
      }
      sc[nt] = a;
    }

    bool diag = (kt == qt);
#pragma unroll
    for (int r = 0; r < 4; ++r) {
      float mx = -1e30f;
#pragma unroll
      for (int nt = 0; nt < 4; ++nt) {
        float s = sc[nt][r] * 0.125f;
        if (diag) {
          int kj = nt * 16 + l15;
          int qi = w * 16 + l4 * 4 + r;
          if (kj > qi) s = -1e30f;
        }
        sc[nt][r] = s;
        mx = fmaxf(mx, s);
      }
      mx = fmaxf(mx, __shfl_xor(mx, 1, 64));
      mx = fmaxf(mx, __shfl_xor(mx, 2, 64));
      mx = fmaxf(mx, __shfl_xor(mx, 4, 64));
      mx = fmaxf(mx, __shfl_xor(mx, 8, 64));
      float mn = fmaxf(m_run[r], mx);
      float scale = __expf(m_run[r] - mn);
      m_run[r] = mn;
      float rs = 0.f;
#pragma unroll
      for (int nt = 0; nt < 4; ++nt) {
        float p = __expf(sc[nt][r] - mn);
        sc[nt][r] = p;
        rs += p;
      }
      rs += __shfl_xor(rs, 1, 64);
      rs += __shfl_xor(rs, 2, 64);
      rs += __shfl_xor(rs, 4, 64);
      rs += __shfl_xor(rs, 8, 64);
      l_run[r] = l_run[r] * scale + rs;
#pragma unroll
      for (int nt = 0; nt < 4; ++nt) acc_o[nt][r] *= scale;
    }

#pragma unroll
    for (int nt = 0; nt < 4; ++nt)
#pragma unroll
      for (int r = 0; r < 4; ++r)
        p_lds[w][(l4 * 4 + r) * 72 + nt * 16 + l15] = (bf16)sc[nt][r];
    asm volatile("s_waitcnt lgkmcnt(0)" ::: "memory");
    __builtin_amdgcn_sched_barrier(0);

#pragma unroll
    for (int kc = 0; kc < 2; ++kc) {
      bf16x8 pf = *(const bf16x8*)&p_lds[w][l15 * 72 + kc * 32 + l4 * 8];
#pragma unroll
      for (int nt = 0; nt < 4; ++nt) {
        bf16x8 vf = *(const bf16x8*)&v_lds[(nt * 16 + l15) * 64 + kc * 32 + l4 * 8];
        acc_o[nt] = __builtin_amdgcn_mfma_f32_16x16x32_bf16(pf, vf, acc_o[nt], 0, 0, 0);
      }
    }
    __syncthreads();
  }

#pragma unroll
  for (int nt = 0; nt < 4; ++nt)
#pragma unroll
    for (int r = 0; r < 4; ++r) {
      float ov = acc_o[nt][r] / l_run[r];
      int s = qt * 64 + w * 16 + l4 * 4 + r;
      o[((size_t)(b * S_ + s)) * D_ + head * 64 + nt * 16 + l15] = (bf16)ov;
    }
}

// =======================================================================
extern "C" void kernel_launch(void* const* d_in, const int* in_sizes, int n_in,
                              void* d_out, int out_size, void* d_ws, size_t ws_size,
                              hipStream_t stream) {
  const int* tokens  = (const int*)d_in[0];
  const float* tok_emb = (const float*)d_in[2];
  const float* wq = (const float*)d_in[3];
  const float* wk = (const float*)d_in[4];
  const float* wv = (const float*)d_in[5];
  const float* wo = (const float*)d_in[6];
  const float* w1 = (const float*)d_in[7];
  const float* w2 = (const float*)d_in[8];
  const float* w3 = (const float*)d_in[9];
  const float* anw = (const float*)d_in[10];
  const float* fnw = (const float*)d_in[11];
  const float* finw = (const float*)d_in[12];
  const float* outw = (const float*)d_in[13];

  (void)hipFuncSetAttribute((const void*)gemm8_bt<0>,
                            hipFuncAttributeMaxDynamicSharedMemorySize, 131072);
  (void)hipFuncSetAttribute((const void*)gemm8_bt<3>,
                            hipFuncAttributeMaxDynamicSharedMemorySize, 131072);

  auto al = [](size_t x) { return (x + 255) & ~(size_t)255; };
  const size_t WTB   = 11272192ull * 2;
  const size_t OUTWTB = (size_t)V_ * D_ * 2;
  const size_t HB   = (size_t)B_ * S_ * D_ * 4;
  const size_t XBB  = (size_t)B_ * S_ * D_ * 2;
  const size_t QKVB = (size_t)B_ * S_ * 1536 * 2;
  const size_t QRB  = (size_t)B_ * HQ_ * S_ * 64 * 2;
  const size_t KRB  = (size_t)B_ * HK_ * S_ * 64 * 2;
  const size_t OB   = (size_t)B_ * S_ * D_ * 2;
  const size_t GATEB = (size_t)B_ * S_ * 2816 * 2;
  const size_t TABB = (size_t)S_ * 32 * 2 * 4;

  size_t fixed = al(OUTWTB) + al(HB) + al(XBB) + al(QKVB) + al(QRB) + al(KRB) + al(KRB) +
                 al(OB) + al(GATEB) + al(TABB);
  bool allup = ws_size >= fixed + 8 * al(WTB) + 4096;
  int nslots = allup ? 8 : 1;

  char* p = (char*)d_ws;
  bf16* wT    = (bf16*)p; p += (size_t)nslots * al(WTB);
  bf16* outwT = (bf16*)p; p += al(OUTWTB);
  float* h    = (float*)p; p += al(HB);
  bf16* xb    = (bf16*)p; p += al(XBB);
  bf16* qkv   = (bf16*)p; p += al(QKVB);
  bf16* q_r   = (bf16*)p; p += al(QRB);
  bf16* k_r   = (bf16*)p; p += al(KRB);
  bf16* vTb   = (bf16*)p; p += al(KRB);
  bf16* ob    = (bf16*)p; p += al(OB);
  bf16* gate  = (bf16*)p; p += al(GATEB);
  float* tab  = (float*)p; p += al(TABB);

  const size_t WTS = al(WTB) / 2;
  const size_t OFF_QKV = 0;
  const size_t OFF_WK  = 1024ull * 1024;
  const size_t OFF_WV  = 1280ull * 1024;
  const size_t OFF_WO  = 1572864ull;
  const size_t OFF_W13 = 2621440ull;       // interleaved w1/w3: 5632 rows x 1024
  const size_t OFF_W2  = 8388608ull;

  auto tr = [&](const float* src, size_t srcStride, bf16* dst, size_t dstStride,
                int Kd, int Nd, int layers, int rowMul, int rowAdd) {
    transpose_cvt<<<dim3(Nd / 32, Kd / 32, layers), 256, 0, stream>>>(
        src, dst, Kd, Nd, (long long)srcStride, (long long)dstStride, rowMul, rowAdd);
  };

  ropetab_k<<<128, 256, 0, stream>>>(tab);
  embed_k<<<B_ * S_, 256, 0, stream>>>(tokens, tok_emb, h);
  tr(outw, 0, outwT, 0, 1024, 32000, 1, 1, 0);

  if (allup) {
    tr(wq, 1024 * 1024, wT + OFF_QKV, WTS, 1024, 1024, 8, 1, 0);
    tr(wk, 1024 * 256,  wT + OFF_WK,  WTS, 1024, 256, 8, 1, 0);
    tr(wv, 1024 * 256,  wT + OFF_WV,  WTS, 1024, 256, 8, 1, 0);
    tr(wo, 1024 * 1024, wT + OFF_WO,  WTS, 1024, 1024, 8, 1, 0);
    tr(w1, 1024 * 2816, wT + OFF_W13, WTS, 1024, 2816, 8, 2, 0);
    tr(w3, 1024 * 2816, wT + OFF_W13, WTS, 1024, 2816, 8, 2, 1);
    tr(w2, 2816 * 1024, wT + OFF_W2,  WTS, 2816, 1024, 8, 1, 0);
  }

  for (int l = 0; l < L_; ++l) {
    bf16* wtl = wT + (allup ? (size_t)l * WTS : 0);
    if (!allup) {
      tr(wq + (size_t)l * 1024 * 1024, 0, wtl + OFF_QKV, 0, 1024, 1024, 1, 1, 0);
      tr(wk + (size_t)l * 1024 * 256,  0, wtl + OFF_WK,  0, 1024, 256, 1, 1, 0);
      tr(wv + (size_t)l * 1024 * 256,  0, wtl + OFF_WV,  0, 1024, 256, 1, 1, 0);
      tr(wo + (size_t)l * 1024 * 1024, 0, wtl + OFF_WO,  0, 1024, 1024, 1, 1, 0);
      tr(w1 + (size_t)l * 1024 * 2816, 0, wtl + OFF_W13, 0, 1024, 2816, 1, 2, 0);
      tr(w3 + (size_t)l * 1024 * 2816, 0, wtl + OFF_W13, 0, 1024, 2816, 1, 2, 1);
      tr(w2 + (size_t)l * 2816 * 1024, 0, wtl + OFF_W2,  0, 2816, 1024, 1, 1, 0);
    }

    rmsnorm_k<<<B_ * S_, 256, 0, stream>>>(h, anw + l * D_, xb);
    gemm_bt<2><<<dim3(16, 12), 256, 0, stream>>>(xb, wtl + OFF_QKV, qkv, nullptr, 2048, 1536, 1024);
    qkvpost_k<<<7168, 256, 0, stream>>>(qkv, tab, q_r, k_r, vTb);
    attn_k<<<B_ * HQ_ * (S_ / 64), 256, 0, stream>>>(q_r, k_r, vTb, ob);
    gemm_bt<1><<<dim3(16, 8), 256, 0, stream>>>(ob, wtl + OFF_WO, h, h, 2048, 1024, 1024);
    rmsnorm_k<<<B_ * S_, 256, 0, stream>>>(h, fnw + l * D_, xb);
    gemm8_bt<3><<<176, 512, 131072, stream>>>(xb, wtl + OFF_W13, gate, nullptr, 5632, 1024);
    gemm_bt<1><<<dim3(16, 8), 256, 0, stream>>>(gate, wtl + OFF_W2, h, h, 2048, 1024, 2816);
  }

  rmsnorm_k<<<B_ * S_, 256, 0, stream>>>(h, finw, xb);
  gemm8_bt<0><<<1000, 512, 131072, stream>>>(xb, outwT, d_out, nullptr, 32000, 1024);
}

// Round 5
// 1883.551 us; speedup vs baseline: 1.2216x; 1.0806x over previous
//
#include <hip/hip_runtime.h>
#include <hip/hip_bf16.h>

typedef __bf16 bf16;
typedef __bf16 bf16x8 __attribute__((ext_vector_type(8)));
typedef float f32x4 __attribute__((ext_vector_type(4)));

#define B_ 2
#define S_ 1024
#define D_ 1024
#define L_ 8
#define HQ_ 16
#define HK_ 4
#define DH_ 64
#define FF_ 2816
#define V_ 32000

// ---------------- embedding gather ----------------
__global__ __launch_bounds__(256) void embed_k(const int* __restrict__ toks,
                                               const float* __restrict__ emb,
                                               float* __restrict__ h) {
  int row = blockIdx.x;
  int tok = toks[row];
  f32x4 v = *(const f32x4*)&emb[(size_t)tok * D_ + threadIdx.x * 4];
  *(f32x4*)&h[(size_t)row * D_ + threadIdx.x * 4] = v;
}

// ---------------- rope table ----------------
__global__ __launch_bounds__(256) void ropetab_k(float* __restrict__ tab) {
  int i = blockIdx.x * 256 + threadIdx.x;
  if (i >= S_ * 32) return;
  int d = i & 31, s = i >> 5;
  float f = expf(-(2.0f * d / 64.0f) * logf(500000.0f));
  float ang = (float)s * f;
  tab[i * 2]     = cosf(ang);
  tab[i * 2 + 1] = sinf(ang);
}

// ---------------- rmsnorm: fp32 in -> bf16 out ----------------
__global__ __launch_bounds__(256) void rmsnorm_k(const float* __restrict__ x,
                                                 const float* __restrict__ w,
                                                 bf16* __restrict__ out) {
  int row = blockIdx.x;
  const float* xr = x + (size_t)row * D_;
  int base = threadIdx.x * 4;
  f32x4 v = *(const f32x4*)&xr[base];
  float ss = v[0]*v[0] + v[1]*v[1] + v[2]*v[2] + v[3]*v[3];
  for (int m = 1; m < 64; m <<= 1) ss += __shfl_xor(ss, m, 64);
  __shared__ float partial[4];
  if ((threadIdx.x & 63) == 0) partial[threadIdx.x >> 6] = ss;
  __syncthreads();
  float tot = partial[0] + partial[1] + partial[2] + partial[3];
  float rr = rsqrtf(tot * (1.0f / D_) + 1e-5f);
  f32x4 wv = *(const f32x4*)&w[base];
  bf16* o = out + (size_t)row * D_ + base;
  o[0] = (bf16)(v[0] * rr * wv[0]);
  o[1] = (bf16)(v[1] * rr * wv[1]);
  o[2] = (bf16)(v[2] * rr * wv[2]);
  o[3] = (bf16)(v[3] * rr * wv[3]);
}

// ---------------- transpose + fp32->bf16 ----------------
__global__ __launch_bounds__(256) void transpose_cvt(const float* __restrict__ src,
                                                     bf16* __restrict__ dst,
                                                     int K, int N,
                                                     long long srcStride, long long dstStride,
                                                     int rowMul, int rowAdd) {
  __shared__ float tile[32][33];
  int bx = blockIdx.x, by = blockIdx.y, z = blockIdx.z;
  src += (size_t)z * srcStride;
  dst += (size_t)z * dstStride;
  int tx = threadIdx.x & 31, ty = threadIdx.x >> 5;
#pragma unroll
  for (int i = 0; i < 4; ++i) {
    int r = ty + i * 8;
    tile[r][tx] = src[(size_t)(by * 32 + r) * N + bx * 32 + tx];
  }
  __syncthreads();
#pragma unroll
  for (int i = 0; i < 4; ++i) {
    int r = ty + i * 8;
    dst[(size_t)((bx * 32 + r) * rowMul + rowAdd) * K + by * 32 + tx] = (bf16)tile[tx][r];
  }
}

// ---------------- BMx128 2-phase GEMM (small-N shapes) ----------------
// BM in {64,128}. 4 waves, wave tile (BM/2)x64. EPI 0: fp32. 1: fp32 +R. 2: bf16.
template <int EPI, int BM>
__global__ __launch_bounds__(256) void gemm_bt(const bf16* __restrict__ A,
                                               const bf16* __restrict__ BT,
                                               void* __restrict__ Cout,
                                               const float* __restrict__ R,
                                               int M, int N, int K) {
  constexpr int MR = BM / 32;      // A-frags per wave
  __shared__ bf16 As[BM * 64];
  __shared__ bf16 Bs[128 * 64];
  const int t = threadIdx.x;
  const int w = t >> 6, l = t & 63;
  const int l15 = l & 15, l4 = l >> 4;
  const int bm = blockIdx.x * BM, bn = blockIdx.y * 128;
  const int wr = w >> 1, wc = w & 1;

  const int srow = t >> 3, scol = (t & 7) * 8;
  const bf16* ag = &A[(size_t)(bm + srow) * K + scol];
  const bf16* bg = &BT[(size_t)(bn + srow) * K + scol];
  const int ldsbase = (t & 192) * 8;

  f32x4 acc[MR][4] = {};

  for (int k0 = 0; k0 < K; k0 += 64) {
#pragma unroll
    for (int i = 0; i < BM / 32; ++i)
      __builtin_amdgcn_global_load_lds(
          (const __attribute__((address_space(1))) void*)(ag + (size_t)(i * 32) * K + k0),
          (__attribute__((address_space(3))) void*)&As[i * 2048 + ldsbase], 16, 0, 0);
#pragma unroll
    for (int i = 0; i < 4; ++i)
      __builtin_amdgcn_global_load_lds(
          (const __attribute__((address_space(1))) void*)(bg + (size_t)(i * 32) * K + k0),
          (__attribute__((address_space(3))) void*)&Bs[i * 2048 + ldsbase], 16, 0, 0);
    __syncthreads();
#pragma unroll
    for (int kc = 0; kc < 2; ++kc) {
      bf16x8 af[MR], bfr[4];
#pragma unroll
      for (int m = 0; m < MR; ++m)
        af[m] = *(const bf16x8*)&As[(wr * (BM / 2) + m * 16 + l15) * 64 + kc * 32 + l4 * 8];
#pragma unroll
      for (int n = 0; n < 4; ++n)
        bfr[n] = *(const bf16x8*)&Bs[(wc * 64 + n * 16 + l15) * 64 + kc * 32 + l4 * 8];
#pragma unroll
      for (int m = 0; m < MR; ++m)
#pragma unroll
        for (int n = 0; n < 4; ++n)
          acc[m][n] = __builtin_amdgcn_mfma_f32_16x16x32_bf16(af[m], bfr[n], acc[m][n], 0, 0, 0);
    }
    __syncthreads();
  }

#pragma unroll
  for (int m = 0; m < MR; ++m)
#pragma unroll
    for (int n = 0; n < 4; ++n)
#pragma unroll
      for (int r = 0; r < 4; ++r) {
        int row = bm + wr * (BM / 2) + m * 16 + l4 * 4 + r;
        int col = bn + wc * 64 + n * 16 + l15;
        size_t ix = (size_t)row * N + col;
        float v = acc[m][n][r];
        if (EPI == 0)      ((float*)Cout)[ix] = v;
        else if (EPI == 1) ((float*)Cout)[ix] = v + R[ix];
        else               ((bf16*)Cout)[ix] = (bf16)v;
      }
}

// ---------------- 256x256 8-phase GEMM, deep-pipeline schedule S2 ----------------
// kc-half-major LDS slabs [256 rows][32 cols] with chunk-XOR swizzle (conflict-free,
// verified r4). Stage schedule: kc1(kt+1) at ph1/ph2, kc0(kt+2) at ph3 (into buf's
// own kc0 slab, free after ph2). Waits after MFMA clusters: vmcnt(8) draining loads
// issued 4-5 phases earlier (~>=900 cyc slack = HBM latency). Peeled 2-iter tail.
// EPI 0: fp32 out.  EPI 3: interleaved-w13 fused silu (even=w1, odd=w3).
template <int EPI>
__global__ __launch_bounds__(512, 2) void gemm8_bt(const bf16* __restrict__ A,
                                                   const bf16* __restrict__ BT,
                                                   void* __restrict__ Cout,
                                                   const float* __restrict__ R,
                                                   int N, int K) {
  extern __shared__ char smem[];   // 131072 B: A [0,65536), B [65536,131072)
  const int t = threadIdx.x;
  const int wid = t >> 6, l = t & 63;
  const int l15 = l & 15, l4 = l >> 4;
  const int wr = wid >> 2, wc = wid & 3;
  const int rsw = (l4 ^ ((l15 >> 1) & 3)) * 16;
  const int csw = ((t & 3) ^ ((t >> 3) & 3)) * 8;

  int nwg = gridDim.x;
  int q = nwg >> 3, r = nwg & 7;
  int xcd = blockIdx.x & 7, jj = blockIdx.x >> 3;
  int L = (xcd < r ? xcd * (q + 1) : r * (q + 1) + (xcd - r) * q) + jj;
  const int bm = (L & 7) * 256, bn = (L >> 3) * 256;

  const int NT = K >> 6;           // assumed >= 3 (K=1024 -> 16)

  auto stage = [&](const bf16* __restrict__ G, int rowbase, int cbase, int buf, int kc, int kt) {
#pragma unroll
    for (int i = 0; i < 2; ++i) {
      int j = i * 512 + t;
      const bf16* src = G + (size_t)(rowbase + (j >> 2)) * K + kt * 64 + kc * 32 + csw;
      __builtin_amdgcn_global_load_lds(
          (const __attribute__((address_space(1))) void*)src,
          (__attribute__((address_space(3))) void*)(smem + cbase + buf * 32768 + kc * 16384 +
                                                    i * 8192 + wid * 1024),
          16, 0, 0);
    }
  };
  auto ldA = [&](int buf, int kc, int m) -> bf16x8 {
    return *(const bf16x8*)(smem + buf * 32768 + kc * 16384 +
                            (wr * 128 + m * 16 + l15) * 64 + rsw);
  };
  auto ldB = [&](int buf, int kc, int n) -> bf16x8 {
    return *(const bf16x8*)(smem + 65536 + buf * 32768 + kc * 16384 +
                            (wc * 64 + n * 16 + l15) * 64 + rsw);
  };

  f32x4 acc[8][4] = {};
  bf16x8 af[4], bq[4];

  auto rd03 = [&](int buf, int kc) {
#pragma unroll
    for (int m = 0; m < 4; ++m) af[m] = ldA(buf, kc, m);
#pragma unroll
    for (int n = 0; n < 4; ++n) bq[n] = ldB(buf, kc, n);
  };
  auto rd47 = [&](int buf, int kc) {
#pragma unroll
    for (int m = 0; m < 4; ++m) af[m] = ldA(buf, kc, 4 + m);
  };
  auto mf_lo = [&]() {
    __builtin_amdgcn_s_setprio(1);
#pragma unroll
    for (int m = 0; m < 4; ++m)
#pragma unroll
      for (int n = 0; n < 4; ++n)
        acc[m][n] = __builtin_amdgcn_mfma_f32_16x16x32_bf16(af[m], bq[n], acc[m][n], 0, 0, 0);
    __builtin_amdgcn_s_setprio(0);
    __builtin_amdgcn_sched_barrier(0);
  };
  auto mf_hi = [&]() {
    __builtin_amdgcn_s_setprio(1);
#pragma unroll
    for (int m = 0; m < 4; ++m)
#pragma unroll
      for (int n = 0; n < 4; ++n)
        acc[4 + m][n] = __builtin_amdgcn_mfma_f32_16x16x32_bf16(af[m], bq[n], acc[4 + m][n], 0, 0, 0);
    __builtin_amdgcn_s_setprio(0);
    __builtin_amdgcn_sched_barrier(0);
  };
#define GBAR { __builtin_amdgcn_sched_barrier(0); __builtin_amdgcn_s_barrier(); }
#define VMW(n) { asm volatile("s_waitcnt vmcnt(" #n ")" ::: "memory"); __builtin_amdgcn_sched_barrier(0); }

  // prologue: kc0(t0), kc1(t0) -> buf0; kc0(t1) -> buf1  (12 loads)
  stage(A, bm, 0, 0, 0, 0);  stage(BT, bn, 65536, 0, 0, 0);
  stage(A, bm, 0, 0, 1, 0);  stage(BT, bn, 65536, 0, 1, 0);
  stage(A, bm, 0, 1, 0, 1);  stage(BT, bn, 65536, 1, 0, 1);
  VMW(8);
  __builtin_amdgcn_s_barrier();

  // steady: kt = 0 .. NT-3   (invariant entering kt: 8 outstanding = kc1(kt)+kc0(kt+1))
  for (int kt = 0; kt < NT - 2; ++kt) {
    const int buf = kt & 1, nbuf = buf ^ 1;
    // ph1: compute kc0 lo; stage A-kc1(kt+1)
    rd03(buf, 0);
    stage(A, bm, 0, nbuf, 1, kt + 1);
    GBAR; mf_lo(); GBAR;
    // ph2: compute kc0 hi; stage B-kc1(kt+1); drain kc1(kt)
    rd47(buf, 0);
    stage(BT, bn, 65536, nbuf, 1, kt + 1);
    GBAR; mf_hi(); VMW(8); __builtin_amdgcn_s_barrier();
    // ph3: compute kc1 lo; stage kc0(kt+2) into buf (slab free after ph2)
    rd03(buf, 1);
    stage(A, bm, 0, buf, 0, kt + 2);
    stage(BT, bn, 65536, buf, 0, kt + 2);
    GBAR; mf_lo(); GBAR;
    // ph4: compute kc1 hi; drain kc0(kt+1)
    rd47(buf, 1);
    GBAR; mf_hi(); VMW(8); __builtin_amdgcn_s_barrier();
  }
  {  // kt = NT-2: no kc0(kt+2) stage; ph4 drains kc0(NT-1) -> vmcnt(4)
    const int kt = NT - 2;
    const int buf = kt & 1, nbuf = buf ^ 1;
    rd03(buf, 0);
    stage(A, bm, 0, nbuf, 1, kt + 1);
    GBAR; mf_lo(); GBAR;
    rd47(buf, 0);
    stage(BT, bn, 65536, nbuf, 1, kt + 1);
    GBAR; mf_hi(); VMW(8); __builtin_amdgcn_s_barrier();
    rd03(buf, 1);
    GBAR; mf_lo(); GBAR;
    rd47(buf, 1);
    GBAR; mf_hi(); VMW(4); __builtin_amdgcn_s_barrier();
  }
  {  // kt = NT-1: no stages; ph2 drains kc1(NT-1) -> vmcnt(0)
    const int buf = (NT - 1) & 1;
    rd03(buf, 0);
    GBAR; mf_lo(); GBAR;
    rd47(buf, 0);
    GBAR; mf_hi(); VMW(0); __builtin_amdgcn_s_barrier();
    rd03(buf, 1);
    GBAR; mf_lo(); GBAR;
    rd47(buf, 1);
    GBAR; mf_hi(); __builtin_amdgcn_s_barrier();
  }
#undef GBAR
#undef VMW

  if (EPI == 3) {
    bf16* G = (bf16*)Cout;
    const int Nc = N >> 1;
#pragma unroll
    for (int m = 0; m < 8; ++m)
#pragma unroll
      for (int n = 0; n < 4; ++n)
#pragma unroll
        for (int rr = 0; rr < 4; ++rr) {
          float v = acc[m][n][rr];
          float part = __shfl_xor(v, 1, 64);
          if (!(l15 & 1)) {
            float a = v, c = part;
            float s = a / (1.0f + __expf(-a));
            int row = bm + wr * 128 + m * 16 + l4 * 4 + rr;
            int col = (bn >> 1) + wc * 32 + n * 8 + (l15 >> 1);
            G[(size_t)row * Nc + col] = (bf16)(s * c);
          }
        }
  } else {
#pragma unroll
    for (int m = 0; m < 8; ++m)
#pragma unroll
      for (int n = 0; n < 4; ++n)
#pragma unroll
        for (int rr = 0; rr < 4; ++rr) {
          int row = bm + wr * 128 + m * 16 + l4 * 4 + rr;
          int col = bn + wc * 64 + n * 16 + l15;
          size_t ix = (size_t)row * N + col;
          float v = acc[m][n][rr];
          if (EPI == 0)      ((float*)Cout)[ix] = v;
          else if (EPI == 1) ((float*)Cout)[ix] = v + R[ix];
          else               ((bf16*)Cout)[ix] = (bf16)v;
        }
  }
}

// ---------------- fused qkv post: rope(q), rope(k), transpose(v) ----------------
__global__ __launch_bounds__(256) void qkvpost_k(const bf16* __restrict__ qkv,
                                                 const float* __restrict__ tab,
                                                 bf16* __restrict__ q_r,
                                                 bf16* __restrict__ k_r,
                                                 bf16* __restrict__ vT) {
  int bid = blockIdx.x;
  if (bid < 4096) {
    int i = bid * 256 + threadIdx.x;
    int d = i & 31, h = (i >> 5) & 15, s = (i >> 9) & 1023, b = i >> 19;
    size_t src = (size_t)(b * S_ + s) * 1536 + h * 64 + 2 * d;
    float a  = (float)qkv[src];
    float bb = (float)qkv[src + 1];
    float c  = tab[(s * 32 + d) * 2];
    float sn = tab[(s * 32 + d) * 2 + 1];
    size_t o = ((size_t)((b * HQ_ + h) * S_ + s)) * 64 + 2 * d;
    q_r[o]     = (bf16)(a * c - bb * sn);
    q_r[o + 1] = (bf16)(a * sn + bb * c);
  } else if (bid < 5120) {
    int i = (bid - 4096) * 256 + threadIdx.x;
    int d = i & 31, h = (i >> 5) & 3, s = (i >> 7) & 1023, b = i >> 17;
    size_t src = (size_t)(b * S_ + s) * 1536 + 1024 + h * 64 + 2 * d;
    float a  = (float)qkv[src];
    float bb = (float)qkv[src + 1];
    float c  = tab[(s * 32 + d) * 2];
    float sn = tab[(s * 32 + d) * 2 + 1];
    size_t o = ((size_t)((b * HK_ + h) * S_ + s)) * 64 + 2 * d;
    k_r[o]     = (bf16)(a * c - bb * sn);
    k_r[o + 1] = (bf16)(a * sn + bb * c);
  } else {
    int i = (bid - 5120) * 256 + threadIdx.x;
    int s = i & 1023, dh = (i >> 10) & 63, h = (i >> 16) & 3, b = i >> 18;
    vT[((size_t)((b * HK_ + h) * 64 + dh)) * S_ + s] =
        qkv[(size_t)(b * S_ + s) * 1536 + 1280 + h * 64 + dh];
  }
}

// ---------------- flash attention (causal, GQA) ----------------
__global__ __launch_bounds__(256) void attn_k(const bf16* __restrict__ q_r,
                                              const bf16* __restrict__ k_r,
                                              const bf16* __restrict__ vT,
                                              bf16* __restrict__ o) {
  __shared__ bf16 k_lds[64 * 64];
  __shared__ bf16 v_lds[64 * 64];
  __shared__ bf16 p_lds[4][16 * 72];
  int t = threadIdx.x, w = t >> 6, l = t & 63, l15 = l & 15, l4 = l >> 4;
  int qt = blockIdx.x & 15, head = (blockIdx.x >> 4) & 15, b = blockIdx.x >> 8;
  int kvh = head >> 2;
  const bf16* qh = q_r + ((size_t)(b * HQ_ + head)) * S_ * 64;
  const bf16* kh = k_r + ((size_t)(b * HK_ + kvh)) * S_ * 64;
  const bf16* vh = vT + ((size_t)(b * HK_ + kvh)) * 64 * S_;
  int q0 = qt * 64 + w * 16;

  bf16x8 aq[2];
  aq[0] = *(const bf16x8*)&qh[(size_t)(q0 + l15) * 64 + l4 * 8];
  aq[1] = *(const bf16x8*)&qh[(size_t)(q0 + l15) * 64 + 32 + l4 * 8];

  f32x4 acc_o[4] = {};
  float m_run[4], l_run[4];
#pragma unroll
  for (int r = 0; r < 4; ++r) { m_run[r] = -1e30f; l_run[r] = 0.f; }

  for (int kt = 0; kt <= qt; ++kt) {
    {
      const bf16* src = kh + kt * 4096;
#pragma unroll
      for (int i = 0; i < 2; ++i) {
        int c = i * 256 + t;
        *(bf16x8*)&k_lds[c * 8] = *(const bf16x8*)&src[c * 8];
      }
#pragma unroll
      for (int i = 0; i < 2; ++i) {
        int c = i * 256 + t;
        int row = c >> 3, col8 = (c & 7) * 8;
        *(bf16x8*)&v_lds[row * 64 + col8] = *(const bf16x8*)&vh[(size_t)row * S_ + kt * 64 + col8];
      }
    }
    __syncthreads();

    f32x4 sc[4];
#pragma unroll
    for (int nt = 0; nt < 4; ++nt) {
      f32x4 a = {};
#pragma unroll
      for (int kc = 0; kc < 2; ++kc) {
        bf16x8 bk = *(const bf16x8*)&k_lds[(nt * 16 + l15) * 64 + kc * 32 + l4 * 8];
        a = __builtin_amdgcn_mfma_f32_16x16x32_bf16(aq[kc], bk, a, 0, 0, 0);
      }
      sc[nt] = a;
    }

    bool diag = (kt == qt);
#pragma unroll
    for (int r = 0; r < 4; ++r) {
      float mx = -1e30f;
#pragma unroll
      for (int nt = 0; nt < 4; ++nt) {
        float s = sc[nt][r] * 0.125f;
        if (diag) {
          int kj = nt * 16 + l15;
          int qi = w * 16 + l4 * 4 + r;
          if (kj > qi) s = -1e30f;
        }
        sc[nt][r] = s;
        mx = fmaxf(mx, s);
      }
      mx = fmaxf(mx, __shfl_xor(mx, 1, 64));
      mx = fmaxf(mx, __shfl_xor(mx, 2, 64));
      mx = fmaxf(mx, __shfl_xor(mx, 4, 64));
      mx = fmaxf(mx, __shfl_xor(mx, 8, 64));
      float mn = fmaxf(m_run[r], mx);
      float scale = __expf(m_run[r] - mn);
      m_run[r] = mn;
      float rs = 0.f;
#pragma unroll
      for (int nt = 0; nt < 4; ++nt) {
        float p = __expf(sc[nt][r] - mn);
        sc[nt][r] = p;
        rs += p;
      }
      rs += __shfl_xor(rs, 1, 64);
      rs += __shfl_xor(rs, 2, 64);
      rs += __shfl_xor(rs, 4, 64);
      rs += __shfl_xor(rs, 8, 64);
      l_run[r] = l_run[r] * scale + rs;
#pragma unroll
      for (int nt = 0; nt < 4; ++nt) acc_o[nt][r] *= scale;
    }

#pragma unroll
    for (int nt = 0; nt < 4; ++nt)
#pragma unroll
      for (int r = 0; r < 4; ++r)
        p_lds[w][(l4 * 4 + r) * 72 + nt * 16 + l15] = (bf16)sc[nt][r];
    asm volatile("s_waitcnt lgkmcnt(0)" ::: "memory");
    __builtin_amdgcn_sched_barrier(0);

#pragma unroll
    for (int kc = 0; kc < 2; ++kc) {
      bf16x8 pf = *(const bf16x8*)&p_lds[w][l15 * 72 + kc * 32 + l4 * 8];
#pragma unroll
      for (int nt = 0; nt < 4; ++nt) {
        bf16x8 vf = *(const bf16x8*)&v_lds[(nt * 16 + l15) * 64 + kc * 32 + l4 * 8];
        acc_o[nt] = __builtin_amdgcn_mfma_f32_16x16x32_bf16(pf, vf, acc_o[nt], 0, 0, 0);
      }
    }
    __syncthreads();
  }

#pragma unroll
  for (int nt = 0; nt < 4; ++nt)
#pragma unroll
    for (int r = 0; r < 4; ++r) {
      float ov = acc_o[nt][r] / l_run[r];
      int s = qt * 64 + w * 16 + l4 * 4 + r;
      o[((size_t)(b * S_ + s)) * D_ + head * 64 + nt * 16 + l15] = (bf16)ov;
    }
}

// =======================================================================
extern "C" void kernel_launch(void* const* d_in, const int* in_sizes, int n_in,
                              void* d_out, int out_size, void* d_ws, size_t ws_size,
                              hipStream_t stream) {
  const int* tokens  = (const int*)d_in[0];
  const float* tok_emb = (const float*)d_in[2];
  const float* wq = (const float*)d_in[3];
  const float* wk = (const float*)d_in[4];
  const float* wv = (const float*)d_in[5];
  const float* wo = (const float*)d_in[6];
  const float* w1 = (const float*)d_in[7];
  const float* w2 = (const float*)d_in[8];
  const float* w3 = (const float*)d_in[9];
  const float* anw = (const float*)d_in[10];
  const float* fnw = (const float*)d_in[11];
  const float* finw = (const float*)d_in[12];
  const float* outw = (const float*)d_in[13];

  (void)hipFuncSetAttribute((const void*)gemm8_bt<0>,
                            hipFuncAttributeMaxDynamicSharedMemorySize, 131072);
  (void)hipFuncSetAttribute((const void*)gemm8_bt<3>,
                            hipFuncAttributeMaxDynamicSharedMemorySize, 131072);

  auto al = [](size_t x) { return (x + 255) & ~(size_t)255; };
  const size_t WTB   = 11272192ull * 2;
  const size_t OUTWTB = (size_t)V_ * D_ * 2;
  const size_t HB   = (size_t)B_ * S_ * D_ * 4;
  const size_t XBB  = (size_t)B_ * S_ * D_ * 2;
  const size_t QKVB = (size_t)B_ * S_ * 1536 * 2;
  const size_t QRB  = (size_t)B_ * HQ_ * S_ * 64 * 2;
  const size_t KRB  = (size_t)B_ * HK_ * S_ * 64 * 2;
  const size_t OB   = (size_t)B_ * S_ * D_ * 2;
  const size_t GATEB = (size_t)B_ * S_ * 2816 * 2;
  const size_t TABB = (size_t)S_ * 32 * 2 * 4;

  size_t fixed = al(OUTWTB) + al(HB) + al(XBB) + al(QKVB) + al(QRB) + al(KRB) + al(KRB) +
                 al(OB) + al(GATEB) + al(TABB);
  bool allup = ws_size >= fixed + 8 * al(WTB) + 4096;
  int nslots = allup ? 8 : 1;

  char* p = (char*)d_ws;
  bf16* wT    = (bf16*)p; p += (size_t)nslots * al(WTB);
  bf16* outwT = (bf16*)p; p += al(OUTWTB);
  float* h    = (float*)p; p += al(HB);
  bf16* xb    = (bf16*)p; p += al(XBB);
  bf16* qkv   = (bf16*)p; p += al(QKVB);
  bf16* q_r   = (bf16*)p; p += al(QRB);
  bf16* k_r   = (bf16*)p; p += al(KRB);
  bf16* vTb   = (bf16*)p; p += al(KRB);
  bf16* ob    = (bf16*)p; p += al(OB);
  bf16* gate  = (bf16*)p; p += al(GATEB);
  float* tab  = (float*)p; p += al(TABB);

  const size_t WTS = al(WTB) / 2;
  const size_t OFF_QKV = 0;
  const size_t OFF_WK  = 1024ull * 1024;
  const size_t OFF_WV  = 1280ull * 1024;
  const size_t OFF_WO  = 1572864ull;
  const size_t OFF_W13 = 2621440ull;       // interleaved w1/w3: 5632 rows x 1024
  const size_t OFF_W2  = 8388608ull;

  auto tr = [&](const float* src, size_t srcStride, bf16* dst, size_t dstStride,
                int Kd, int Nd, int layers, int rowMul, int rowAdd) {
    transpose_cvt<<<dim3(Nd / 32, Kd / 32, layers), 256, 0, stream>>>(
        src, dst, Kd, Nd, (long long)srcStride, (long long)dstStride, rowMul, rowAdd);
  };

  ropetab_k<<<128, 256, 0, stream>>>(tab);
  embed_k<<<B_ * S_, 256, 0, stream>>>(tokens, tok_emb, h);
  tr(outw, 0, outwT, 0, 1024, 32000, 1, 1, 0);

  if (allup) {
    tr(wq, 1024 * 1024, wT + OFF_QKV, WTS, 1024, 1024, 8, 1, 0);
    tr(wk, 1024 * 256,  wT + OFF_WK,  WTS, 1024, 256, 8, 1, 0);
    tr(wv, 1024 * 256,  wT + OFF_WV,  WTS, 1024, 256, 8, 1, 0);
    tr(wo, 1024 * 1024, wT + OFF_WO,  WTS, 1024, 1024, 8, 1, 0);
    tr(w1, 1024 * 2816, wT + OFF_W13, WTS, 1024, 2816, 8, 2, 0);
    tr(w3, 1024 * 2816, wT + OFF_W13, WTS, 1024, 2816, 8, 2, 1);
    tr(w2, 2816 * 1024, wT + OFF_W2,  WTS, 2816, 1024, 8, 1, 0);
  }

  for (int l = 0; l < L_; ++l) {
    bf16* wtl = wT + (allup ? (size_t)l * WTS : 0);
    if (!allup) {
      tr(wq + (size_t)l * 1024 * 1024, 0, wtl + OFF_QKV, 0, 1024, 1024, 1, 1, 0);
      tr(wk + (size_t)l * 1024 * 256,  0, wtl + OFF_WK,  0, 1024, 256, 1, 1, 0);
      tr(wv + (size_t)l * 1024 * 256,  0, wtl + OFF_WV,  0, 1024, 256, 1, 1, 0);
      tr(wo + (size_t)l * 1024 * 1024, 0, wtl + OFF_WO,  0, 1024, 1024, 1, 1, 0);
      tr(w1 + (size_t)l * 1024 * 2816, 0, wtl + OFF_W13, 0, 1024, 2816, 1, 2, 0);
      tr(w3 + (size_t)l * 1024 * 2816, 0, wtl + OFF_W13, 0, 1024, 2816, 1, 2, 1);
      tr(w2 + (size_t)l * 2816 * 1024, 0, wtl + OFF_W2,  0, 2816, 1024, 1, 1, 0);
    }

    rmsnorm_k<<<B_ * S_, 256, 0, stream>>>(h, anw + l * D_, xb);
    gemm_bt<2, 128><<<dim3(16, 12), 256, 0, stream>>>(xb, wtl + OFF_QKV, qkv, nullptr, 2048, 1536, 1024);
    qkvpost_k<<<7168, 256, 0, stream>>>(qkv, tab, q_r, k_r, vTb);
    attn_k<<<B_ * HQ_ * (S_ / 64), 256, 0, stream>>>(q_r, k_r, vTb, ob);
    gemm_bt<1, 64><<<dim3(32, 8), 256, 0, stream>>>(ob, wtl + OFF_WO, h, h, 2048, 1024, 1024);
    rmsnorm_k<<<B_ * S_, 256, 0, stream>>>(h, fnw + l * D_, xb);
    gemm8_bt<3><<<176, 512, 131072, stream>>>(xb, wtl + OFF_W13, gate, nullptr, 5632, 1024);
    gemm_bt<1, 64><<<dim3(32, 8), 256, 0, stream>>>(gate, wtl + OFF_W2, h, h, 2048, 1024, 2816);
  }

  rmsnorm_k<<<B_ * S_, 256, 0, stream>>>(h, finw, xb);
  gemm8_bt<0><<<1000, 512, 131072, stream>>>(xb, outwT, d_out, nullptr, 32000, 1024);
}

// Round 6
// 1809.103 us; speedup vs baseline: 1.2719x; 1.0412x over previous
//
#include <hip/hip_runtime.h>
#include <hip/hip_bf16.h>

typedef __bf16 bf16;
typedef __bf16 bf16x8 __attribute__((ext_vector_type(8)));
typedef float f32x4 __attribute__((ext_vector_type(4)));

#define B_ 2
#define S_ 1024
#define D_ 1024
#define L_ 8
#define HQ_ 16
#define HK_ 4
#define DH_ 64
#define FF_ 2816
#define V_ 32000

// ---------------- embedding gather ----------------
__global__ __launch_bounds__(256) void embed_k(const int* __restrict__ toks,
                                               const float* __restrict__ emb,
                                               float* __restrict__ h) {
  int row = blockIdx.x;
  int tok = toks[row];
  f32x4 v = *(const f32x4*)&emb[(size_t)tok * D_ + threadIdx.x * 4];
  *(f32x4*)&h[(size_t)row * D_ + threadIdx.x * 4] = v;
}

// ---------------- rope table ----------------
__global__ __launch_bounds__(256) void ropetab_k(float* __restrict__ tab) {
  int i = blockIdx.x * 256 + threadIdx.x;
  if (i >= S_ * 32) return;
  int d = i & 31, s = i >> 5;
  float f = expf(-(2.0f * d / 64.0f) * logf(500000.0f));
  float ang = (float)s * f;
  tab[i * 2]     = cosf(ang);
  tab[i * 2 + 1] = sinf(ang);
}

// ---------------- rmsnorm: fp32 in -> bf16 out ----------------
__global__ __launch_bounds__(256) void rmsnorm_k(const float* __restrict__ x,
                                                 const float* __restrict__ w,
                                                 bf16* __restrict__ out) {
  int row = blockIdx.x;
  const float* xr = x + (size_t)row * D_;
  int base = threadIdx.x * 4;
  f32x4 v = *(const f32x4*)&xr[base];
  float ss = v[0]*v[0] + v[1]*v[1] + v[2]*v[2] + v[3]*v[3];
  for (int m = 1; m < 64; m <<= 1) ss += __shfl_xor(ss, m, 64);
  __shared__ float partial[4];
  if ((threadIdx.x & 63) == 0) partial[threadIdx.x >> 6] = ss;
  __syncthreads();
  float tot = partial[0] + partial[1] + partial[2] + partial[3];
  float rr = rsqrtf(tot * (1.0f / D_) + 1e-5f);
  f32x4 wv = *(const f32x4*)&w[base];
  bf16* o = out + (size_t)row * D_ + base;
  o[0] = (bf16)(v[0] * rr * wv[0]);
  o[1] = (bf16)(v[1] * rr * wv[1]);
  o[2] = (bf16)(v[2] * rr * wv[2]);
  o[3] = (bf16)(v[3] * rr * wv[3]);
}

// ---------------- transpose + fp32->bf16 ----------------
__global__ __launch_bounds__(256) void transpose_cvt(const float* __restrict__ src,
                                                     bf16* __restrict__ dst,
                                                     int K, int N,
                                                     long long srcStride, long long dstStride,
                                                     int rowMul, int rowAdd) {
  __shared__ float tile[32][33];
  int bx = blockIdx.x, by = blockIdx.y, z = blockIdx.z;
  src += (size_t)z * srcStride;
  dst += (size_t)z * dstStride;
  int tx = threadIdx.x & 31, ty = threadIdx.x >> 5;
#pragma unroll
  for (int i = 0; i < 4; ++i) {
    int r = ty + i * 8;
    tile[r][tx] = src[(size_t)(by * 32 + r) * N + bx * 32 + tx];
  }
  __syncthreads();
#pragma unroll
  for (int i = 0; i < 4; ++i) {
    int r = ty + i * 8;
    dst[(size_t)((bx * 32 + r) * rowMul + rowAdd) * K + by * 32 + tx] = (bf16)tile[tx][r];
  }
}

// ---------------- BMx128 2-phase GEMM (small-N shapes) ----------------
template <int EPI, int BM>
__global__ __launch_bounds__(256) void gemm_bt(const bf16* __restrict__ A,
                                               const bf16* __restrict__ BT,
                                               void* __restrict__ Cout,
                                               const float* __restrict__ R,
                                               int M, int N, int K) {
  constexpr int MR = BM / 32;
  __shared__ bf16 As[BM * 64];
  __shared__ bf16 Bs[128 * 64];
  const int t = threadIdx.x;
  const int w = t >> 6, l = t & 63;
  const int l15 = l & 15, l4 = l >> 4;
  const int bm = blockIdx.x * BM, bn = blockIdx.y * 128;
  const int wr = w >> 1, wc = w & 1;

  const int srow = t >> 3, scol = (t & 7) * 8;
  const bf16* ag = &A[(size_t)(bm + srow) * K + scol];
  const bf16* bg = &BT[(size_t)(bn + srow) * K + scol];
  const int ldsbase = (t & 192) * 8;

  f32x4 acc[MR][4] = {};

  for (int k0 = 0; k0 < K; k0 += 64) {
#pragma unroll
    for (int i = 0; i < BM / 32; ++i)
      __builtin_amdgcn_global_load_lds(
          (const __attribute__((address_space(1))) void*)(ag + (size_t)(i * 32) * K + k0),
          (__attribute__((address_space(3))) void*)&As[i * 2048 + ldsbase], 16, 0, 0);
#pragma unroll
    for (int i = 0; i < 4; ++i)
      __builtin_amdgcn_global_load_lds(
          (const __attribute__((address_space(1))) void*)(bg + (size_t)(i * 32) * K + k0),
          (__attribute__((address_space(3))) void*)&Bs[i * 2048 + ldsbase], 16, 0, 0);
    __syncthreads();
#pragma unroll
    for (int kc = 0; kc < 2; ++kc) {
      bf16x8 af[MR], bfr[4];
#pragma unroll
      for (int m = 0; m < MR; ++m)
        af[m] = *(const bf16x8*)&As[(wr * (BM / 2) + m * 16 + l15) * 64 + kc * 32 + l4 * 8];
#pragma unroll
      for (int n = 0; n < 4; ++n)
        bfr[n] = *(const bf16x8*)&Bs[(wc * 64 + n * 16 + l15) * 64 + kc * 32 + l4 * 8];
#pragma unroll
      for (int m = 0; m < MR; ++m)
#pragma unroll
        for (int n = 0; n < 4; ++n)
          acc[m][n] = __builtin_amdgcn_mfma_f32_16x16x32_bf16(af[m], bfr[n], acc[m][n], 0, 0, 0);
    }
    __syncthreads();
  }

#pragma unroll
  for (int m = 0; m < MR; ++m)
#pragma unroll
    for (int n = 0; n < 4; ++n)
#pragma unroll
      for (int r = 0; r < 4; ++r) {
        int row = bm + wr * (BM / 2) + m * 16 + l4 * 4 + r;
        int col = bn + wc * 64 + n * 16 + l15;
        size_t ix = (size_t)row * N + col;
        float v = acc[m][n][r];
        if (EPI == 0)      ((float*)Cout)[ix] = v;
        else if (EPI == 1) ((float*)Cout)[ix] = v + R[ix];
        else               ((bf16*)Cout)[ix] = (bf16)v;
      }
}

// ---------------- 128x128 8-wave deep-pipeline GEMM (M=2048; N%128==0) ----------------
// 2 blocks/CU (64KB LDS, <=128 VGPR). kc-half-major slabs [128][32], row stride 64B,
// chunk-XOR swizzle (conflict-free). One barrier per phase; counted vmcnt(4);
// stage targets proven free by barrier chain (ph1 -> other buf; ph2 -> own kc0 slab).
// EPI 0: fp32. 2: bf16. 3: interleaved-w13 fused silu (even=w1, odd=w3).
template <int EPI>
__global__ __launch_bounds__(512, 4) void gemm8_bt(const bf16* __restrict__ A,
                                                   const bf16* __restrict__ BT,
                                                   void* __restrict__ Cout,
                                                   const float* __restrict__ R,
                                                   int N, int K) {
  extern __shared__ char smem[];   // 65536: A [0,32768) B [32768,65536); slab=buf*16384+kc*8192
  const int t = threadIdx.x;
  const int wid = t >> 6, l = t & 63;
  const int l15 = l & 15, l4 = l >> 4;
  const int wr = wid >> 1, wc = wid & 1;
  const int rsw = (l4 ^ ((l15 >> 1) & 3)) * 16;
  const int csw = ((t & 3) ^ ((t >> 3) & 3)) * 8;

  int nwg = gridDim.x;                       // %8 == 0 for all call sites
  int q = nwg >> 3;
  int xcd = blockIdx.x & 7, jj = blockIdx.x >> 3;
  int L = xcd * q + jj;
  const int bm = (L & 15) * 128, bn = (L >> 4) * 128;

  const int NT = K >> 6;

  auto stage = [&](const bf16* __restrict__ G, int rowbase, int obase, int buf, int kc, int kt) {
    const bf16* src = G + (size_t)(rowbase + (t >> 2)) * K + kt * 64 + kc * 32 + csw;
    __builtin_amdgcn_global_load_lds(
        (const __attribute__((address_space(1))) void*)src,
        (__attribute__((address_space(3))) void*)(smem + obase + buf * 16384 + kc * 8192 +
                                                  wid * 1024),
        16, 0, 0);
  };
  auto ldA = [&](int buf, int kc, int m) -> bf16x8 {
    return *(const bf16x8*)(smem + buf * 16384 + kc * 8192 +
                            (wr * 32 + m * 16 + l15) * 64 + rsw);
  };
  auto ldB = [&](int buf, int kc, int n) -> bf16x8 {
    return *(const bf16x8*)(smem + 32768 + buf * 16384 + kc * 8192 +
                            (wc * 64 + n * 16 + l15) * 64 + rsw);
  };

  f32x4 acc[2][4] = {};
  bf16x8 af[2], bq[4];

  auto rdph = [&](int buf, int kc) {
#pragma unroll
    for (int m = 0; m < 2; ++m) af[m] = ldA(buf, kc, m);
#pragma unroll
    for (int n = 0; n < 4; ++n) bq[n] = ldB(buf, kc, n);
  };
  auto mf = [&]() {
    __builtin_amdgcn_s_setprio(1);
#pragma unroll
    for (int m = 0; m < 2; ++m)
#pragma unroll
      for (int n = 0; n < 4; ++n)
        acc[m][n] = __builtin_amdgcn_mfma_f32_16x16x32_bf16(af[m], bq[n], acc[m][n], 0, 0, 0);
    __builtin_amdgcn_s_setprio(0);
    __builtin_amdgcn_sched_barrier(0);
  };
#define SCB __builtin_amdgcn_sched_barrier(0)
#define VMW4 { asm volatile("s_waitcnt vmcnt(4)" ::: "memory"); SCB; }
#define VMW2 { asm volatile("s_waitcnt vmcnt(2)" ::: "memory"); SCB; }
#define VMW0 { asm volatile("s_waitcnt vmcnt(0)" ::: "memory"); SCB; }
#define SBAR { __builtin_amdgcn_s_barrier(); SCB; }

  // prologue: A0B0(0), A1B1(0), A0B0(1); drain tile0-kc0; invariant: 4 outstanding
  stage(A, bm, 0, 0, 0, 0);  stage(BT, bn, 32768, 0, 0, 0);
  stage(A, bm, 0, 0, 1, 0);  stage(BT, bn, 32768, 0, 1, 0);
  stage(A, bm, 0, 1, 0, 1);  stage(BT, bn, 32768, 1, 0, 1);
  VMW4; __builtin_amdgcn_s_barrier();

  for (int kt = 0; kt < NT - 2; ++kt) {
    const int buf = kt & 1, nbuf = buf ^ 1;
    // ph1: kc0; stage kc1(kt+1) -> nbuf
    rdph(buf, 0);
    stage(A, bm, 0, nbuf, 1, kt + 1);
    stage(BT, bn, 32768, nbuf, 1, kt + 1);
    SCB; mf(); VMW4; SBAR;
    // ph2: kc1; stage kc0(kt+2) -> buf (slab freed by ph1's closing barrier)
    rdph(buf, 1);
    stage(A, bm, 0, buf, 0, kt + 2);
    stage(BT, bn, 32768, buf, 0, kt + 2);
    SCB; mf(); VMW4; SBAR;
  }
  {  // kt = NT-2
    const int buf = (NT - 2) & 1, nbuf = buf ^ 1;
    rdph(buf, 0);
    stage(A, bm, 0, nbuf, 1, NT - 1);
    stage(BT, bn, 32768, nbuf, 1, NT - 1);
    SCB; mf(); VMW4; SBAR;
    rdph(buf, 1);
    SCB; mf(); VMW2; SBAR;
  }
  {  // kt = NT-1
    const int buf = (NT - 1) & 1;
    rdph(buf, 0);
    SCB; mf(); VMW0; SBAR;
    rdph(buf, 1);
    SCB; mf();
  }
#undef SCB
#undef VMW4
#undef VMW2
#undef VMW0
#undef SBAR

  if (EPI == 3) {
    bf16* G = (bf16*)Cout;
    const int Nc = N >> 1;
#pragma unroll
    for (int m = 0; m < 2; ++m)
#pragma unroll
      for (int n = 0; n < 4; ++n)
#pragma unroll
        for (int rr = 0; rr < 4; ++rr) {
          float v = acc[m][n][rr];
          float part = __shfl_xor(v, 1, 64);
          if (!(l15 & 1)) {
            float a = v, c = part;
            float s = a / (1.0f + __expf(-a));
            int row = bm + wr * 32 + m * 16 + l4 * 4 + rr;
            int col = (bn >> 1) + wc * 32 + n * 8 + (l15 >> 1);
            G[(size_t)row * Nc + col] = (bf16)(s * c);
          }
        }
  } else {
#pragma unroll
    for (int m = 0; m < 2; ++m)
#pragma unroll
      for (int n = 0; n < 4; ++n)
#pragma unroll
        for (int rr = 0; rr < 4; ++rr) {
          int row = bm + wr * 32 + m * 16 + l4 * 4 + rr;
          int col = bn + wc * 64 + n * 16 + l15;
          size_t ix = (size_t)row * N + col;
          float v = acc[m][n][rr];
          if (EPI == 0)      ((float*)Cout)[ix] = v;
          else               ((bf16*)Cout)[ix] = (bf16)v;
        }
  }
}

// ---------------- fused qkv post: rope(q), rope(k), transpose(v) ----------------
__global__ __launch_bounds__(256) void qkvpost_k(const bf16* __restrict__ qkv,
                                                 const float* __restrict__ tab,
                                                 bf16* __restrict__ q_r,
                                                 bf16* __restrict__ k_r,
                                                 bf16* __restrict__ vT) {
  int bid = blockIdx.x;
  if (bid < 4096) {
    int i = bid * 256 + threadIdx.x;
    int d = i & 31, h = (i >> 5) & 15, s = (i >> 9) & 1023, b = i >> 19;
    size_t src = (size_t)(b * S_ + s) * 1536 + h * 64 + 2 * d;
    float a  = (float)qkv[src];
    float bb = (float)qkv[src + 1];
    float c  = tab[(s * 32 + d) * 2];
    float sn = tab[(s * 32 + d) * 2 + 1];
    size_t o = ((size_t)((b * HQ_ + h) * S_ + s)) * 64 + 2 * d;
    q_r[o]     = (bf16)(a * c - bb * sn);
    q_r[o + 1] = (bf16)(a * sn + bb * c);
  } else if (bid < 5120) {
    int i = (bid - 4096) * 256 + threadIdx.x;
    int d = i & 31, h = (i >> 5) & 3, s = (i >> 7) & 1023, b = i >> 17;
    size_t src = (size_t)(b * S_ + s) * 1536 + 1024 + h * 64 + 2 * d;
    float a  = (float)qkv[src];
    float bb = (float)qkv[src + 1];
    float c  = tab[(s * 32 + d) * 2];
    float sn = tab[(s * 32 + d) * 2 + 1];
    size_t o = ((size_t)((b * HK_ + h) * S_ + s)) * 64 + 2 * d;
    k_r[o]     = (bf16)(a * c - bb * sn);
    k_r[o + 1] = (bf16)(a * sn + bb * c);
  } else {
    int i = (bid - 5120) * 256 + threadIdx.x;
    int s = i & 1023, dh = (i >> 10) & 63, h = (i >> 16) & 3, b = i >> 18;
    vT[((size_t)((b * HK_ + h) * 64 + dh)) * S_ + s] =
        qkv[(size_t)(b * S_ + s) * 1536 + 1280 + h * 64 + dh];
  }
}

// ---------------- flash attention (causal, GQA) with T14 async-stage ----------------
__global__ __launch_bounds__(256) void attn_k(const bf16* __restrict__ q_r,
                                              const bf16* __restrict__ k_r,
                                              const bf16* __restrict__ vT,
                                              bf16* __restrict__ o) {
  __shared__ bf16 k_lds[64 * 64];
  __shared__ bf16 v_lds[64 * 64];
  __shared__ bf16 p_lds[4][16 * 72];
  int t = threadIdx.x, w = t >> 6, l = t & 63, l15 = l & 15, l4 = l >> 4;
  int qt = blockIdx.x & 15, head = (blockIdx.x >> 4) & 15, b = blockIdx.x >> 8;
  int kvh = head >> 2;
  const bf16* qh = q_r + ((size_t)(b * HQ_ + head)) * S_ * 64;
  const bf16* kh = k_r + ((size_t)(b * HK_ + kvh)) * S_ * 64;
  const bf16* vh = vT + ((size_t)(b * HK_ + kvh)) * 64 * S_;
  int q0 = qt * 64 + w * 16;

  bf16x8 aq[2];
  aq[0] = *(const bf16x8*)&qh[(size_t)(q0 + l15) * 64 + l4 * 8];
  aq[1] = *(const bf16x8*)&qh[(size_t)(q0 + l15) * 64 + 32 + l4 * 8];

  f32x4 acc_o[4] = {};
  float m_run[4], l_run[4];
#pragma unroll
  for (int r = 0; r < 4; ++r) { m_run[r] = -1e30f; l_run[r] = 0.f; }

  // T14: preload tile 0 into registers
  bf16x8 gk[2], gv[2];
#pragma unroll
  for (int i = 0; i < 2; ++i) {
    int c = i * 256 + t;
    gk[i] = *(const bf16x8*)&kh[c * 8];
    gv[i] = *(const bf16x8*)&vh[(size_t)(c >> 3) * S_ + (c & 7) * 8];
  }

  for (int kt = 0; kt <= qt; ++kt) {
    // write register-staged tile kt to LDS
#pragma unroll
    for (int i = 0; i < 2; ++i) {
      int c = i * 256 + t;
      *(bf16x8*)&k_lds[c * 8] = gk[i];
      *(bf16x8*)&v_lds[(c >> 3) * 64 + (c & 7) * 8] = gv[i];
    }
    __syncthreads();

    // issue next tile's global loads (latency hides under QK/softmax/PV)
    bf16x8 gkn[2], gvn[2];
    if (kt < qt) {
      const bf16* srck = kh + (kt + 1) * 4096;
#pragma unroll
      for (int i = 0; i < 2; ++i) {
        int c = i * 256 + t;
        gkn[i] = *(const bf16x8*)&srck[c * 8];
        gvn[i] = *(const bf16x8*)&vh[(size_t)(c >> 3) * S_ + (kt + 1) * 64 + (c & 7) * 8];
      }
    }

    f32x4 sc[4];
#pragma unroll
    for (int nt = 0; nt < 4; ++nt) {
      f32x4 a = {};
#pragma unroll
      for (int kc = 0; kc < 2; ++kc) {
        bf16x8 bk = *(const bf16x8*)&k_lds[(nt * 16 + l15) * 64 + kc * 32 + l4 * 8];
        a = __builtin_amdgcn_mfma_f32_16x16x32_bf16(aq[kc], bk, a, 0, 0, 0);
      }
      sc[nt] = a;
    }

    bool diag = (kt == qt);
#pragma unroll
    for (int r = 0; r < 4; ++r) {
      float mx = -1e30f;
#pragma unroll
      for (int nt = 0; nt < 4; ++nt) {
        float s = sc[nt][r] * 0.125f;
        if (diag) {
          int kj = nt * 16 + l15;
          int qi = w * 16 + l4 * 4 + r;
          if (kj > qi) s = -1e30f;
        }
        sc[nt][r] = s;
        mx = fmaxf(mx, s);
      }
      mx = fmaxf(mx, __shfl_xor(mx, 1, 64));
      mx = fmaxf(mx, __shfl_xor(mx, 2, 64));
      mx = fmaxf(mx, __shfl_xor(mx, 4, 64));
      mx = fmaxf(mx, __shfl_xor(mx, 8, 64));
      float mn = fmaxf(m_run[r], mx);
      float scale = __expf(m_run[r] - mn);
      m_run[r] = mn;
      float rs = 0.f;
#pragma unroll
      for (int nt = 0; nt < 4; ++nt) {
        float p = __expf(sc[nt][r] - mn);
        sc[nt][r] = p;
        rs += p;
      }
      rs += __shfl_xor(rs, 1, 64);
      rs += __shfl_xor(rs, 2, 64);
      rs += __shfl_xor(rs, 4, 64);
      rs += __shfl_xor(rs, 8, 64);
      l_run[r] = l_run[r] * scale + rs;
#pragma unroll
      for (int nt = 0; nt < 4; ++nt) acc_o[nt][r] *= scale;
    }

#pragma unroll
    for (int nt = 0; nt < 4; ++nt)
#pragma unroll
      for (int r = 0; r < 4; ++r)
        p_lds[w][(l4 * 4 + r) * 72 + nt * 16 + l15] = (bf16)sc[nt][r];
    asm volatile("s_waitcnt lgkmcnt(0)" ::: "memory");
    __builtin_amdgcn_sched_barrier(0);

#pragma unroll
    for (int kc = 0; kc < 2; ++kc) {
      bf16x8 pf = *(const bf16x8*)&p_lds[w][l15 * 72 + kc * 32 + l4 * 8];
#pragma unroll
      for (int nt = 0; nt < 4; ++nt) {
        bf16x8 vf = *(const bf16x8*)&v_lds[(nt * 16 + l15) * 64 + kc * 32 + l4 * 8];
        acc_o[nt] = __builtin_amdgcn_mfma_f32_16x16x32_bf16(pf, vf, acc_o[nt], 0, 0, 0);
      }
    }
    __syncthreads();

#pragma unroll
    for (int i = 0; i < 2; ++i) { gk[i] = gkn[i]; gv[i] = gvn[i]; }
  }

#pragma unroll
  for (int nt = 0; nt < 4; ++nt)
#pragma unroll
    for (int r = 0; r < 4; ++r) {
      float ov = acc_o[nt][r] / l_run[r];
      int s = qt * 64 + w * 16 + l4 * 4 + r;
      o[((size_t)(b * S_ + s)) * D_ + head * 64 + nt * 16 + l15] = (bf16)ov;
    }
}

// =======================================================================
extern "C" void kernel_launch(void* const* d_in, const int* in_sizes, int n_in,
                              void* d_out, int out_size, void* d_ws, size_t ws_size,
                              hipStream_t stream) {
  const int* tokens  = (const int*)d_in[0];
  const float* tok_emb = (const float*)d_in[2];
  const float* wq = (const float*)d_in[3];
  const float* wk = (const float*)d_in[4];
  const float* wv = (const float*)d_in[5];
  const float* wo = (const float*)d_in[6];
  const float* w1 = (const float*)d_in[7];
  const float* w2 = (const float*)d_in[8];
  const float* w3 = (const float*)d_in[9];
  const float* anw = (const float*)d_in[10];
  const float* fnw = (const float*)d_in[11];
  const float* finw = (const float*)d_in[12];
  const float* outw = (const float*)d_in[13];

  (void)hipFuncSetAttribute((const void*)gemm8_bt<0>,
                            hipFuncAttributeMaxDynamicSharedMemorySize, 65536);
  (void)hipFuncSetAttribute((const void*)gemm8_bt<2>,
                            hipFuncAttributeMaxDynamicSharedMemorySize, 65536);
  (void)hipFuncSetAttribute((const void*)gemm8_bt<3>,
                            hipFuncAttributeMaxDynamicSharedMemorySize, 65536);

  auto al = [](size_t x) { return (x + 255) & ~(size_t)255; };
  const size_t WTB   = 11272192ull * 2;
  const size_t OUTWTB = (size_t)V_ * D_ * 2;
  const size_t HB   = (size_t)B_ * S_ * D_ * 4;
  const size_t XBB  = (size_t)B_ * S_ * D_ * 2;
  const size_t QKVB = (size_t)B_ * S_ * 1536 * 2;
  const size_t QRB  = (size_t)B_ * HQ_ * S_ * 64 * 2;
  const size_t KRB  = (size_t)B_ * HK_ * S_ * 64 * 2;
  const size_t OB   = (size_t)B_ * S_ * D_ * 2;
  const size_t GATEB = (size_t)B_ * S_ * 2816 * 2;
  const size_t TABB = (size_t)S_ * 32 * 2 * 4;

  size_t fixed = al(OUTWTB) + al(HB) + al(XBB) + al(QKVB) + al(QRB) + al(KRB) + al(KRB) +
                 al(OB) + al(GATEB) + al(TABB);
  bool allup = ws_size >= fixed + 8 * al(WTB) + 4096;
  int nslots = allup ? 8 : 1;

  char* p = (char*)d_ws;
  bf16* wT    = (bf16*)p; p += (size_t)nslots * al(WTB);
  bf16* outwT = (bf16*)p; p += al(OUTWTB);
  float* h    = (float*)p; p += al(HB);
  bf16* xb    = (bf16*)p; p += al(XBB);
  bf16* qkv   = (bf16*)p; p += al(QKVB);
  bf16* q_r   = (bf16*)p; p += al(QRB);
  bf16* k_r   = (bf16*)p; p += al(KRB);
  bf16* vTb   = (bf16*)p; p += al(KRB);
  bf16* ob    = (bf16*)p; p += al(OB);
  bf16* gate  = (bf16*)p; p += al(GATEB);
  float* tab  = (float*)p; p += al(TABB);

  const size_t WTS = al(WTB) / 2;
  const size_t OFF_QKV = 0;
  const size_t OFF_WK  = 1024ull * 1024;
  const size_t OFF_WV  = 1280ull * 1024;
  const size_t OFF_WO  = 1572864ull;
  const size_t OFF_W13 = 2621440ull;       // interleaved w1/w3: 5632 rows x 1024
  const size_t OFF_W2  = 8388608ull;

  auto tr = [&](const float* src, size_t srcStride, bf16* dst, size_t dstStride,
                int Kd, int Nd, int layers, int rowMul, int rowAdd) {
    transpose_cvt<<<dim3(Nd / 32, Kd / 32, layers), 256, 0, stream>>>(
        src, dst, Kd, Nd, (long long)srcStride, (long long)dstStride, rowMul, rowAdd);
  };

  ropetab_k<<<128, 256, 0, stream>>>(tab);
  embed_k<<<B_ * S_, 256, 0, stream>>>(tokens, tok_emb, h);
  tr(outw, 0, outwT, 0, 1024, 32000, 1, 1, 0);

  if (allup) {
    tr(wq, 1024 * 1024, wT + OFF_QKV, WTS, 1024, 1024, 8, 1, 0);
    tr(wk, 1024 * 256,  wT + OFF_WK,  WTS, 1024, 256, 8, 1, 0);
    tr(wv, 1024 * 256,  wT + OFF_WV,  WTS, 1024, 256, 8, 1, 0);
    tr(wo, 1024 * 1024, wT + OFF_WO,  WTS, 1024, 1024, 8, 1, 0);
    tr(w1, 1024 * 2816, wT + OFF_W13, WTS, 1024, 2816, 8, 2, 0);
    tr(w3, 1024 * 2816, wT + OFF_W13, WTS, 1024, 2816, 8, 2, 1);
    tr(w2, 2816 * 1024, wT + OFF_W2,  WTS, 2816, 1024, 8, 1, 0);
  }

  for (int l = 0; l < L_; ++l) {
    bf16* wtl = wT + (allup ? (size_t)l * WTS : 0);
    if (!allup) {
      tr(wq + (size_t)l * 1024 * 1024, 0, wtl + OFF_QKV, 0, 1024, 1024, 1, 1, 0);
      tr(wk + (size_t)l * 1024 * 256,  0, wtl + OFF_WK,  0, 1024, 256, 1, 1, 0);
      tr(wv + (size_t)l * 1024 * 256,  0, wtl + OFF_WV,  0, 1024, 256, 1, 1, 0);
      tr(wo + (size_t)l * 1024 * 1024, 0, wtl + OFF_WO,  0, 1024, 1024, 1, 1, 0);
      tr(w1 + (size_t)l * 1024 * 2816, 0, wtl + OFF_W13, 0, 1024, 2816, 1, 2, 0);
      tr(w3 + (size_t)l * 1024 * 2816, 0, wtl + OFF_W13, 0, 1024, 2816, 1, 2, 1);
      tr(w2 + (size_t)l * 2816 * 1024, 0, wtl + OFF_W2,  0, 2816, 1024, 1, 1, 0);
    }

    rmsnorm_k<<<B_ * S_, 256, 0, stream>>>(h, anw + l * D_, xb);
    gemm8_bt<2><<<192, 512, 65536, stream>>>(xb, wtl + OFF_QKV, qkv, nullptr, 1536, 1024);
    qkvpost_k<<<7168, 256, 0, stream>>>(qkv, tab, q_r, k_r, vTb);
    attn_k<<<B_ * HQ_ * (S_ / 64), 256, 0, stream>>>(q_r, k_r, vTb, ob);
    gemm_bt<1, 64><<<dim3(32, 8), 256, 0, stream>>>(ob, wtl + OFF_WO, h, h, 2048, 1024, 1024);
    rmsnorm_k<<<B_ * S_, 256, 0, stream>>>(h, fnw + l * D_, xb);
    gemm8_bt<3><<<704, 512, 65536, stream>>>(xb, wtl + OFF_W13, gate, nullptr, 5632, 1024);
    gemm_bt<1, 64><<<dim3(32, 8), 256, 0, stream>>>(gate, wtl + OFF_W2, h, h, 2048, 1024, 2816);
  }

  rmsnorm_k<<<B_ * S_, 256, 0, stream>>>(h, finw, xb);
  gemm8_bt<0><<<4000, 512, 65536, stream>>>(xb, outwT, d_out, nullptr, 32000, 1024);
}

// Round 7
// 1746.134 us; speedup vs baseline: 1.3178x; 1.0361x over previous
//
#include <hip/hip_runtime.h>
#include <hip/hip_bf16.h>

typedef __bf16 bf16;
typedef __bf16 bf16x8 __attribute__((ext_vector_type(8)));
typedef float f32x4 __attribute__((ext_vector_type(4)));

#define B_ 2
#define S_ 1024
#define D_ 1024
#define L_ 8
#define HQ_ 16
#define HK_ 4
#define DH_ 64
#define FF_ 2816
#define V_ 32000

// ---------------- embedding gather ----------------
__global__ __launch_bounds__(256) void embed_k(const int* __restrict__ toks,
                                               const float* __restrict__ emb,
                                               float* __restrict__ h) {
  int row = blockIdx.x;
  int tok = toks[row];
  f32x4 v = *(const f32x4*)&emb[(size_t)tok * D_ + threadIdx.x * 4];
  *(f32x4*)&h[(size_t)row * D_ + threadIdx.x * 4] = v;
}

// ---------------- rope table ----------------
__global__ __launch_bounds__(256) void ropetab_k(float* __restrict__ tab) {
  int i = blockIdx.x * 256 + threadIdx.x;
  if (i >= S_ * 32) return;
  int d = i & 31, s = i >> 5;
  float f = expf(-(2.0f * d / 64.0f) * logf(500000.0f));
  float ang = (float)s * f;
  tab[i * 2]     = cosf(ang);
  tab[i * 2 + 1] = sinf(ang);
}

// ---------------- rmsnorm: fp32 in -> bf16 out ----------------
__global__ __launch_bounds__(256) void rmsnorm_k(const float* __restrict__ x,
                                                 const float* __restrict__ w,
                                                 bf16* __restrict__ out) {
  int row = blockIdx.x;
  const float* xr = x + (size_t)row * D_;
  int base = threadIdx.x * 4;
  f32x4 v = *(const f32x4*)&xr[base];
  float ss = v[0]*v[0] + v[1]*v[1] + v[2]*v[2] + v[3]*v[3];
  for (int m = 1; m < 64; m <<= 1) ss += __shfl_xor(ss, m, 64);
  __shared__ float partial[4];
  if ((threadIdx.x & 63) == 0) partial[threadIdx.x >> 6] = ss;
  __syncthreads();
  float tot = partial[0] + partial[1] + partial[2] + partial[3];
  float rr = rsqrtf(tot * (1.0f / D_) + 1e-5f);
  f32x4 wv = *(const f32x4*)&w[base];
  bf16* o = out + (size_t)row * D_ + base;
  o[0] = (bf16)(v[0] * rr * wv[0]);
  o[1] = (bf16)(v[1] * rr * wv[1]);
  o[2] = (bf16)(v[2] * rr * wv[2]);
  o[3] = (bf16)(v[3] * rr * wv[3]);
}

// ---------------- transpose + fp32->bf16 ----------------
__global__ __launch_bounds__(256) void transpose_cvt(const float* __restrict__ src,
                                                     bf16* __restrict__ dst,
                                                     int K, int N,
                                                     long long srcStride, long long dstStride,
                                                     int rowMul, int rowAdd) {
  __shared__ float tile[32][33];
  int bx = blockIdx.x, by = blockIdx.y, z = blockIdx.z;
  src += (size_t)z * srcStride;
  dst += (size_t)z * dstStride;
  int tx = threadIdx.x & 31, ty = threadIdx.x >> 5;
#pragma unroll
  for (int i = 0; i < 4; ++i) {
    int r = ty + i * 8;
    tile[r][tx] = src[(size_t)(by * 32 + r) * N + bx * 32 + tx];
  }
  __syncthreads();
#pragma unroll
  for (int i = 0; i < 4; ++i) {
    int r = ty + i * 8;
    dst[(size_t)((bx * 32 + r) * rowMul + rowAdd) * K + by * 32 + tx] = (bf16)tile[tx][r];
  }
}

// ---------------- BMx128 2-phase GEMM (small-N shapes) ----------------
template <int EPI, int BM>
__global__ __launch_bounds__(256) void gemm_bt(const bf16* __restrict__ A,
                                               const bf16* __restrict__ BT,
                                               void* __restrict__ Cout,
                                               const float* __restrict__ R,
                                               int M, int N, int K) {
  constexpr int MR = BM / 32;
  __shared__ bf16 As[BM * 64];
  __shared__ bf16 Bs[128 * 64];
  const int t = threadIdx.x;
  const int w = t >> 6, l = t & 63;
  const int l15 = l & 15, l4 = l >> 4;
  const int bm = blockIdx.x * BM, bn = blockIdx.y * 128;
  const int wr = w >> 1, wc = w & 1;

  const int srow = t >> 3, scol = (t & 7) * 8;
  const bf16* ag = &A[(size_t)(bm + srow) * K + scol];
  const bf16* bg = &BT[(size_t)(bn + srow) * K + scol];
  const int ldsbase = (t & 192) * 8;

  f32x4 acc[MR][4] = {};

  for (int k0 = 0; k0 < K; k0 += 64) {
#pragma unroll
    for (int i = 0; i < BM / 32; ++i)
      __builtin_amdgcn_global_load_lds(
          (const __attribute__((address_space(1))) void*)(ag + (size_t)(i * 32) * K + k0),
          (__attribute__((address_space(3))) void*)&As[i * 2048 + ldsbase], 16, 0, 0);
#pragma unroll
    for (int i = 0; i < 4; ++i)
      __builtin_amdgcn_global_load_lds(
          (const __attribute__((address_space(1))) void*)(bg + (size_t)(i * 32) * K + k0),
          (__attribute__((address_space(3))) void*)&Bs[i * 2048 + ldsbase], 16, 0, 0);
    __syncthreads();
#pragma unroll
    for (int kc = 0; kc < 2; ++kc) {
      bf16x8 af[MR], bfr[4];
#pragma unroll
      for (int m = 0; m < MR; ++m)
        af[m] = *(const bf16x8*)&As[(wr * (BM / 2) + m * 16 + l15) * 64 + kc * 32 + l4 * 8];
#pragma unroll
      for (int n = 0; n < 4; ++n)
        bfr[n] = *(const bf16x8*)&Bs[(wc * 64 + n * 16 + l15) * 64 + kc * 32 + l4 * 8];
#pragma unroll
      for (int m = 0; m < MR; ++m)
#pragma unroll
        for (int n = 0; n < 4; ++n)
          acc[m][n] = __builtin_amdgcn_mfma_f32_16x16x32_bf16(af[m], bfr[n], acc[m][n], 0, 0, 0);
    }
    __syncthreads();
  }

#pragma unroll
  for (int m = 0; m < MR; ++m)
#pragma unroll
    for (int n = 0; n < 4; ++n)
#pragma unroll
      for (int r = 0; r < 4; ++r) {
        int row = bm + wr * (BM / 2) + m * 16 + l4 * 4 + r;
        int col = bn + wc * 64 + n * 16 + l15;
        size_t ix = (size_t)row * N + col;
        float v = acc[m][n][r];
        if (EPI == 0)      ((float*)Cout)[ix] = v;
        else if (EPI == 1) ((float*)Cout)[ix] = v + R[ix];
        else               ((bf16*)Cout)[ix] = (bf16)v;
      }
}

// ---------------- 256x256 8-phase GEMM, deep-pipeline S2 (logits; M=2048, N%256==0) ----------------
// Proven r5: 165us @ N=32000, FETCH 106MB. 1 blk/CU, high arithmetic intensity.
template <int EPI>
__global__ __launch_bounds__(512, 2) void gemm256_bt(const bf16* __restrict__ A,
                                                     const bf16* __restrict__ BT,
                                                     void* __restrict__ Cout,
                                                     const float* __restrict__ R,
                                                     int N, int K) {
  extern __shared__ char smem[];   // 131072 B: A [0,65536), B [65536,131072)
  const int t = threadIdx.x;
  const int wid = t >> 6, l = t & 63;
  const int l15 = l & 15, l4 = l >> 4;
  const int wr = wid >> 2, wc = wid & 3;
  const int rsw = (l4 ^ ((l15 >> 1) & 3)) * 16;
  const int csw = ((t & 3) ^ ((t >> 3) & 3)) * 8;

  int nwg = gridDim.x;
  int q = nwg >> 3, r = nwg & 7;
  int xcd = blockIdx.x & 7, jj = blockIdx.x >> 3;
  int L = (xcd < r ? xcd * (q + 1) : r * (q + 1) + (xcd - r) * q) + jj;
  const int bm = (L & 7) * 256, bn = (L >> 3) * 256;

  const int NT = K >> 6;

  auto stage = [&](const bf16* __restrict__ G, int rowbase, int cbase, int buf, int kc, int kt) {
#pragma unroll
    for (int i = 0; i < 2; ++i) {
      int j = i * 512 + t;
      const bf16* src = G + (size_t)(rowbase + (j >> 2)) * K + kt * 64 + kc * 32 + csw;
      __builtin_amdgcn_global_load_lds(
          (const __attribute__((address_space(1))) void*)src,
          (__attribute__((address_space(3))) void*)(smem + cbase + buf * 32768 + kc * 16384 +
                                                    i * 8192 + wid * 1024),
          16, 0, 0);
    }
  };
  auto ldA = [&](int buf, int kc, int m) -> bf16x8 {
    return *(const bf16x8*)(smem + buf * 32768 + kc * 16384 +
                            (wr * 128 + m * 16 + l15) * 64 + rsw);
  };
  auto ldB = [&](int buf, int kc, int n) -> bf16x8 {
    return *(const bf16x8*)(smem + 65536 + buf * 32768 + kc * 16384 +
                            (wc * 64 + n * 16 + l15) * 64 + rsw);
  };

  f32x4 acc[8][4] = {};
  bf16x8 af[4], bq[4];

  auto rd03 = [&](int buf, int kc) {
#pragma unroll
    for (int m = 0; m < 4; ++m) af[m] = ldA(buf, kc, m);
#pragma unroll
    for (int n = 0; n < 4; ++n) bq[n] = ldB(buf, kc, n);
  };
  auto rd47 = [&](int buf, int kc) {
#pragma unroll
    for (int m = 0; m < 4; ++m) af[m] = ldA(buf, kc, 4 + m);
  };
  auto mf_lo = [&]() {
    __builtin_amdgcn_s_setprio(1);
#pragma unroll
    for (int m = 0; m < 4; ++m)
#pragma unroll
      for (int n = 0; n < 4; ++n)
        acc[m][n] = __builtin_amdgcn_mfma_f32_16x16x32_bf16(af[m], bq[n], acc[m][n], 0, 0, 0);
    __builtin_amdgcn_s_setprio(0);
    __builtin_amdgcn_sched_barrier(0);
  };
  auto mf_hi = [&]() {
    __builtin_amdgcn_s_setprio(1);
#pragma unroll
    for (int m = 0; m < 4; ++m)
#pragma unroll
      for (int n = 0; n < 4; ++n)
        acc[4 + m][n] = __builtin_amdgcn_mfma_f32_16x16x32_bf16(af[m], bq[n], acc[4 + m][n], 0, 0, 0);
    __builtin_amdgcn_s_setprio(0);
    __builtin_amdgcn_sched_barrier(0);
  };
#define GBAR { __builtin_amdgcn_sched_barrier(0); __builtin_amdgcn_s_barrier(); }
#define VMW(n) { asm volatile("s_waitcnt vmcnt(" #n ")" ::: "memory"); __builtin_amdgcn_sched_barrier(0); }

  stage(A, bm, 0, 0, 0, 0);  stage(BT, bn, 65536, 0, 0, 0);
  stage(A, bm, 0, 0, 1, 0);  stage(BT, bn, 65536, 0, 1, 0);
  stage(A, bm, 0, 1, 0, 1);  stage(BT, bn, 65536, 1, 0, 1);
  VMW(8);
  __builtin_amdgcn_s_barrier();

  for (int kt = 0; kt < NT - 2; ++kt) {
    const int buf = kt & 1, nbuf = buf ^ 1;
    rd03(buf, 0);
    stage(A, bm, 0, nbuf, 1, kt + 1);
    GBAR; mf_lo(); GBAR;
    rd47(buf, 0);
    stage(BT, bn, 65536, nbuf, 1, kt + 1);
    GBAR; mf_hi(); VMW(8); __builtin_amdgcn_s_barrier();
    rd03(buf, 1);
    stage(A, bm, 0, buf, 0, kt + 2);
    stage(BT, bn, 65536, buf, 0, kt + 2);
    GBAR; mf_lo(); GBAR;
    rd47(buf, 1);
    GBAR; mf_hi(); VMW(8); __builtin_amdgcn_s_barrier();
  }
  {
    const int kt = NT - 2;
    const int buf = kt & 1, nbuf = buf ^ 1;
    rd03(buf, 0);
    stage(A, bm, 0, nbuf, 1, kt + 1);
    GBAR; mf_lo(); GBAR;
    rd47(buf, 0);
    stage(BT, bn, 65536, nbuf, 1, kt + 1);
    GBAR; mf_hi(); VMW(8); __builtin_amdgcn_s_barrier();
    rd03(buf, 1);
    GBAR; mf_lo(); GBAR;
    rd47(buf, 1);
    GBAR; mf_hi(); VMW(4); __builtin_amdgcn_s_barrier();
  }
  {
    const int buf = (NT - 1) & 1;
    rd03(buf, 0);
    GBAR; mf_lo(); GBAR;
    rd47(buf, 0);
    GBAR; mf_hi(); VMW(0); __builtin_amdgcn_s_barrier();
    rd03(buf, 1);
    GBAR; mf_lo(); GBAR;
    rd47(buf, 1);
    GBAR; mf_hi(); __builtin_amdgcn_s_barrier();
  }
#undef GBAR
#undef VMW

#pragma unroll
  for (int m = 0; m < 8; ++m)
#pragma unroll
    for (int n = 0; n < 4; ++n)
#pragma unroll
      for (int rr = 0; rr < 4; ++rr) {
        int row = bm + wr * 128 + m * 16 + l4 * 4 + rr;
        int col = bn + wc * 64 + n * 16 + l15;
        size_t ix = (size_t)row * N + col;
        float v = acc[m][n][rr];
        if (EPI == 0)      ((float*)Cout)[ix] = v;
        else if (EPI == 1) ((float*)Cout)[ix] = v + R[ix];
        else               ((bf16*)Cout)[ix] = (bf16)v;
      }
}

// ---------------- 128x128 8-wave deep-pipeline GEMM (qkv, w13; M=2048, N%128==0) ----------------
template <int EPI>
__global__ __launch_bounds__(512, 4) void gemm8_bt(const bf16* __restrict__ A,
                                                   const bf16* __restrict__ BT,
                                                   void* __restrict__ Cout,
                                                   const float* __restrict__ R,
                                                   int N, int K) {
  extern __shared__ char smem[];   // 65536
  const int t = threadIdx.x;
  const int wid = t >> 6, l = t & 63;
  const int l15 = l & 15, l4 = l >> 4;
  const int wr = wid >> 1, wc = wid & 1;
  const int rsw = (l4 ^ ((l15 >> 1) & 3)) * 16;
  const int csw = ((t & 3) ^ ((t >> 3) & 3)) * 8;

  int nwg = gridDim.x;
  int q = nwg >> 3;
  int xcd = blockIdx.x & 7, jj = blockIdx.x >> 3;
  int L = xcd * q + jj;
  const int bm = (L & 15) * 128, bn = (L >> 4) * 128;

  const int NT = K >> 6;

  auto stage = [&](const bf16* __restrict__ G, int rowbase, int obase, int buf, int kc, int kt) {
    const bf16* src = G + (size_t)(rowbase + (t >> 2)) * K + kt * 64 + kc * 32 + csw;
    __builtin_amdgcn_global_load_lds(
        (const __attribute__((address_space(1))) void*)src,
        (__attribute__((address_space(3))) void*)(smem + obase + buf * 16384 + kc * 8192 +
                                                  wid * 1024),
        16, 0, 0);
  };
  auto ldA = [&](int buf, int kc, int m) -> bf16x8 {
    return *(const bf16x8*)(smem + buf * 16384 + kc * 8192 +
                            (wr * 32 + m * 16 + l15) * 64 + rsw);
  };
  auto ldB = [&](int buf, int kc, int n) -> bf16x8 {
    return *(const bf16x8*)(smem + 32768 + buf * 16384 + kc * 8192 +
                            (wc * 64 + n * 16 + l15) * 64 + rsw);
  };

  f32x4 acc[2][4] = {};
  bf16x8 af[2], bq[4];

  auto rdph = [&](int buf, int kc) {
#pragma unroll
    for (int m = 0; m < 2; ++m) af[m] = ldA(buf, kc, m);
#pragma unroll
    for (int n = 0; n < 4; ++n) bq[n] = ldB(buf, kc, n);
  };
  auto mf = [&]() {
    __builtin_amdgcn_s_setprio(1);
#pragma unroll
    for (int m = 0; m < 2; ++m)
#pragma unroll
      for (int n = 0; n < 4; ++n)
        acc[m][n] = __builtin_amdgcn_mfma_f32_16x16x32_bf16(af[m], bq[n], acc[m][n], 0, 0, 0);
    __builtin_amdgcn_s_setprio(0);
    __builtin_amdgcn_sched_barrier(0);
  };
#define SCB __builtin_amdgcn_sched_barrier(0)
#define VMW4 { asm volatile("s_waitcnt vmcnt(4)" ::: "memory"); SCB; }
#define VMW2 { asm volatile("s_waitcnt vmcnt(2)" ::: "memory"); SCB; }
#define VMW0 { asm volatile("s_waitcnt vmcnt(0)" ::: "memory"); SCB; }
#define SBAR { __builtin_amdgcn_s_barrier(); SCB; }

  stage(A, bm, 0, 0, 0, 0);  stage(BT, bn, 32768, 0, 0, 0);
  stage(A, bm, 0, 0, 1, 0);  stage(BT, bn, 32768, 0, 1, 0);
  stage(A, bm, 0, 1, 0, 1);  stage(BT, bn, 32768, 1, 0, 1);
  VMW4; __builtin_amdgcn_s_barrier();

  for (int kt = 0; kt < NT - 2; ++kt) {
    const int buf = kt & 1, nbuf = buf ^ 1;
    rdph(buf, 0);
    stage(A, bm, 0, nbuf, 1, kt + 1);
    stage(BT, bn, 32768, nbuf, 1, kt + 1);
    SCB; mf(); VMW4; SBAR;
    rdph(buf, 1);
    stage(A, bm, 0, buf, 0, kt + 2);
    stage(BT, bn, 32768, buf, 0, kt + 2);
    SCB; mf(); VMW4; SBAR;
  }
  {
    const int buf = (NT - 2) & 1, nbuf = buf ^ 1;
    rdph(buf, 0);
    stage(A, bm, 0, nbuf, 1, NT - 1);
    stage(BT, bn, 32768, nbuf, 1, NT - 1);
    SCB; mf(); VMW4; SBAR;
    rdph(buf, 1);
    SCB; mf(); VMW2; SBAR;
  }
  {
    const int buf = (NT - 1) & 1;
    rdph(buf, 0);
    SCB; mf(); VMW0; SBAR;
    rdph(buf, 1);
    SCB; mf();
  }
#undef SCB
#undef VMW4
#undef VMW2
#undef VMW0
#undef SBAR

  if (EPI == 3) {
    bf16* G = (bf16*)Cout;
    const int Nc = N >> 1;
#pragma unroll
    for (int m = 0; m < 2; ++m)
#pragma unroll
      for (int n = 0; n < 4; ++n)
#pragma unroll
        for (int rr = 0; rr < 4; ++rr) {
          float v = acc[m][n][rr];
          float part = __shfl_xor(v, 1, 64);
          if (!(l15 & 1)) {
            float a = v, c = part;
            float s = a / (1.0f + __expf(-a));
            int row = bm + wr * 32 + m * 16 + l4 * 4 + rr;
            int col = (bn >> 1) + wc * 32 + n * 8 + (l15 >> 1);
            G[(size_t)row * Nc + col] = (bf16)(s * c);
          }
        }
  } else {
#pragma unroll
    for (int m = 0; m < 2; ++m)
#pragma unroll
      for (int n = 0; n < 4; ++n)
#pragma unroll
        for (int rr = 0; rr < 4; ++rr) {
          int row = bm + wr * 32 + m * 16 + l4 * 4 + rr;
          int col = bn + wc * 64 + n * 16 + l15;
          size_t ix = (size_t)row * N + col;
          float v = acc[m][n][rr];
          if (EPI == 0)      ((float*)Cout)[ix] = v;
          else               ((bf16*)Cout)[ix] = (bf16)v;
        }
  }
}

// ---------------- fused qkv post (vectorized): rope(q)*scale, rope(k), vT tile-transpose ----------------
__global__ __launch_bounds__(256) void qkvpost_k(const bf16* __restrict__ qkv,
                                                 const float* __restrict__ tab,
                                                 bf16* __restrict__ q_r,
                                                 bf16* __restrict__ k_r,
                                                 bf16* __restrict__ vT) {
  int bid = blockIdx.x, t = threadIdx.x;
  if (bid < 1024) {                      // rope q: 4 pairs (8 bf16) per thread
    int i = bid * 256 + t;               // 262144 items
    int g = i & 7, hh = (i >> 3) & 15, s = (i >> 7) & 1023, b = i >> 17;
    bf16x8 v = *(const bf16x8*)&qkv[(size_t)(b * S_ + s) * 1536 + hh * 64 + g * 8];
    f32x4 tc0 = *(const f32x4*)&tab[(s * 32 + g * 4) * 2];
    f32x4 tc1 = *(const f32x4*)&tab[(s * 32 + g * 4) * 2 + 4];
    bf16x8 o;
#pragma unroll
    for (int j = 0; j < 4; ++j) {
      float a = (float)v[2 * j], bb = (float)v[2 * j + 1];
      float c  = (j < 2 ? tc0 : tc1)[(j & 1) * 2];
      float sn = (j < 2 ? tc0 : tc1)[(j & 1) * 2 + 1];
      o[2 * j]     = (bf16)((a * c - bb * sn) * 0.125f);   // fold 1/sqrt(DH)
      o[2 * j + 1] = (bf16)((a * sn + bb * c) * 0.125f);
    }
    *(bf16x8*)&q_r[((size_t)((b * HQ_ + hh) * S_ + s)) * 64 + g * 8] = o;
  } else if (bid < 1280) {               // rope k
    int i = (bid - 1024) * 256 + t;      // 65536 items
    int g = i & 7, hh = (i >> 3) & 3, s = (i >> 5) & 1023, b = i >> 15;
    bf16x8 v = *(const bf16x8*)&qkv[(size_t)(b * S_ + s) * 1536 + 1024 + hh * 64 + g * 8];
    f32x4 tc0 = *(const f32x4*)&tab[(s * 32 + g * 4) * 2];
    f32x4 tc1 = *(const f32x4*)&tab[(s * 32 + g * 4) * 2 + 4];
    bf16x8 o;
#pragma unroll
    for (int j = 0; j < 4; ++j) {
      float a = (float)v[2 * j], bb = (float)v[2 * j + 1];
      float c  = (j < 2 ? tc0 : tc1)[(j & 1) * 2];
      float sn = (j < 2 ? tc0 : tc1)[(j & 1) * 2 + 1];
      o[2 * j]     = (bf16)(a * c - bb * sn);
      o[2 * j + 1] = (bf16)(a * sn + bb * c);
    }
    *(bf16x8*)&k_r[((size_t)((b * HK_ + hh) * S_ + s)) * 64 + g * 8] = o;
  } else {                               // v transpose via LDS 64x64 tile
    __shared__ bf16 vt[64][66];
    int vb = bid - 1280;                 // 128 blocks: b(1) h(2) st(4... ) -> 2*4*16
    int b = vb >> 6, hh = (vb >> 4) & 3, s0 = (vb & 15) * 64;
#pragma unroll
    for (int it = 0; it < 2; ++it) {
      int idx = it * 256 + t;
      int s = idx >> 3, g = idx & 7;
      bf16x8 v = *(const bf16x8*)&qkv[(size_t)(b * S_ + s0 + s) * 1536 + 1280 + hh * 64 + g * 8];
      *(bf16x8*)&vt[s][g * 8] = v;       // note: vt row stride 66, stores unaligned-safe? g*8 even ✓
    }
    __syncthreads();
#pragma unroll
    for (int it = 0; it < 2; ++it) {
      int idx = it * 256 + t;
      int dh = idx >> 3, sg = idx & 7;
      bf16x8 o;
#pragma unroll
      for (int j = 0; j < 8; ++j) o[j] = vt[sg * 8 + j][dh];
      *(bf16x8*)&vT[((size_t)((b * HK_ + hh) * 64 + dh)) * S_ + s0 + sg * 8] = o;
    }
  }
}

// ---------------- flash attention (causal, GQA; Q pre-scaled) with T14 async-stage ----------------
__global__ __launch_bounds__(256) void attn_k(const bf16* __restrict__ q_r,
                                              const bf16* __restrict__ k_r,
                                              const bf16* __restrict__ vT,
                                              bf16* __restrict__ o) {
  __shared__ bf16 k_lds[64 * 64];
  __shared__ bf16 v_lds[64 * 64];
  __shared__ bf16 p_lds[4][16 * 72];
  int t = threadIdx.x, w = t >> 6, l = t & 63, l15 = l & 15, l4 = l >> 4;
  int qt = blockIdx.x & 15, head = (blockIdx.x >> 4) & 15, b = blockIdx.x >> 8;
  int kvh = head >> 2;
  const bf16* qh = q_r + ((size_t)(b * HQ_ + head)) * S_ * 64;
  const bf16* kh = k_r + ((size_t)(b * HK_ + kvh)) * S_ * 64;
  const bf16* vh = vT + ((size_t)(b * HK_ + kvh)) * 64 * S_;
  int q0 = qt * 64 + w * 16;

  bf16x8 aq[2];
  aq[0] = *(const bf16x8*)&qh[(size_t)(q0 + l15) * 64 + l4 * 8];
  aq[1] = *(const bf16x8*)&qh[(size_t)(q0 + l15) * 64 + 32 + l4 * 8];

  f32x4 acc_o[4] = {};
  float m_run[4], l_run[4];
#pragma unroll
  for (int r = 0; r < 4; ++r) { m_run[r] = -1e30f; l_run[r] = 0.f; }

  bf16x8 gk[2], gv[2];
#pragma unroll
  for (int i = 0; i < 2; ++i) {
    int c = i * 256 + t;
    gk[i] = *(const bf16x8*)&kh[c * 8];
    gv[i] = *(const bf16x8*)&vh[(size_t)(c >> 3) * S_ + (c & 7) * 8];
  }

  for (int kt = 0; kt <= qt; ++kt) {
#pragma unroll
    for (int i = 0; i < 2; ++i) {
      int c = i * 256 + t;
      *(bf16x8*)&k_lds[c * 8] = gk[i];
      *(bf16x8*)&v_lds[(c >> 3) * 64 + (c & 7) * 8] = gv[i];
    }
    __syncthreads();

    bf16x8 gkn[2], gvn[2];
    if (kt < qt) {
      const bf16* srck = kh + (kt + 1) * 4096;
#pragma unroll
      for (int i = 0; i < 2; ++i) {
        int c = i * 256 + t;
        gkn[i] = *(const bf16x8*)&srck[c * 8];
        gvn[i] = *(const bf16x8*)&vh[(size_t)(c >> 3) * S_ + (kt + 1) * 64 + (c & 7) * 8];
      }
    }

    f32x4 sc[4];
#pragma unroll
    for (int nt = 0; nt < 4; ++nt) {
      f32x4 a = {};
#pragma unroll
      for (int kc = 0; kc < 2; ++kc) {
        bf16x8 bk = *(const bf16x8*)&k_lds[(nt * 16 + l15) * 64 + kc * 32 + l4 * 8];
        a = __builtin_amdgcn_mfma_f32_16x16x32_bf16(aq[kc], bk, a, 0, 0, 0);
      }
      sc[nt] = a;
    }

    bool diag = (kt == qt);
#pragma unroll
    for (int r = 0; r < 4; ++r) {
      float mx = -1e30f;
#pragma unroll
      for (int nt = 0; nt < 4; ++nt) {
        float s = sc[nt][r];
        if (diag) {
          int kj = nt * 16 + l15;
          int qi = w * 16 + l4 * 4 + r;
          if (kj > qi) s = -1e30f;
        }
        sc[nt][r] = s;
        mx = fmaxf(mx, s);
      }
      mx = fmaxf(mx, __shfl_xor(mx, 1, 64));
      mx = fmaxf(mx, __shfl_xor(mx, 2, 64));
      mx = fmaxf(mx, __shfl_xor(mx, 4, 64));
      mx = fmaxf(mx, __shfl_xor(mx, 8, 64));
      float mn = fmaxf(m_run[r], mx);
      float scale = __expf(m_run[r] - mn);
      m_run[r] = mn;
      float rs = 0.f;
#pragma unroll
      for (int nt = 0; nt < 4; ++nt) {
        float p = __expf(sc[nt][r] - mn);
        sc[nt][r] = p;
        rs += p;
      }
      rs += __shfl_xor(rs, 1, 64);
      rs += __shfl_xor(rs, 2, 64);
      rs += __shfl_xor(rs, 4, 64);
      rs += __shfl_xor(rs, 8, 64);
      l_run[r] = l_run[r] * scale + rs;
#pragma unroll
      for (int nt = 0; nt < 4; ++nt) acc_o[nt][r] *= scale;
    }

#pragma unroll
    for (int nt = 0; nt < 4; ++nt)
#pragma unroll
      for (int r = 0; r < 4; ++r)
        p_lds[w][(l4 * 4 + r) * 72 + nt * 16 + l15] = (bf16)sc[nt][r];
    asm volatile("s_waitcnt lgkmcnt(0)" ::: "memory");
    __builtin_amdgcn_sched_barrier(0);

#pragma unroll
    for (int kc = 0; kc < 2; ++kc) {
      bf16x8 pf = *(const bf16x8*)&p_lds[w][l15 * 72 + kc * 32 + l4 * 8];
#pragma unroll
      for (int nt = 0; nt < 4; ++nt) {
        bf16x8 vf = *(const bf16x8*)&v_lds[(nt * 16 + l15) * 64 + kc * 32 + l4 * 8];
        acc_o[nt] = __builtin_amdgcn_mfma_f32_16x16x32_bf16(pf, vf, acc_o[nt], 0, 0, 0);
      }
    }
    __syncthreads();

#pragma unroll
    for (int i = 0; i < 2; ++i) { gk[i] = gkn[i]; gv[i] = gvn[i]; }
  }

#pragma unroll
  for (int nt = 0; nt < 4; ++nt)
#pragma unroll
    for (int r = 0; r < 4; ++r) {
      float ov = acc_o[nt][r] / l_run[r];
      int s = qt * 64 + w * 16 + l4 * 4 + r;
      o[((size_t)(b * S_ + s)) * D_ + head * 64 + nt * 16 + l15] = (bf16)ov;
    }
}

// =======================================================================
extern "C" void kernel_launch(void* const* d_in, const int* in_sizes, int n_in,
                              void* d_out, int out_size, void* d_ws, size_t ws_size,
                              hipStream_t stream) {
  const int* tokens  = (const int*)d_in[0];
  const float* tok_emb = (const float*)d_in[2];
  const float* wq = (const float*)d_in[3];
  const float* wk = (const float*)d_in[4];
  const float* wv = (const float*)d_in[5];
  const float* wo = (const float*)d_in[6];
  const float* w1 = (const float*)d_in[7];
  const float* w2 = (const float*)d_in[8];
  const float* w3 = (const float*)d_in[9];
  const float* anw = (const float*)d_in[10];
  const float* fnw = (const float*)d_in[11];
  const float* finw = (const float*)d_in[12];
  const float* outw = (const float*)d_in[13];

  (void)hipFuncSetAttribute((const void*)gemm256_bt<0>,
                            hipFuncAttributeMaxDynamicSharedMemorySize, 131072);
  (void)hipFuncSetAttribute((const void*)gemm8_bt<2>,
                            hipFuncAttributeMaxDynamicSharedMemorySize, 65536);
  (void)hipFuncSetAttribute((const void*)gemm8_bt<3>,
                            hipFuncAttributeMaxDynamicSharedMemorySize, 65536);

  auto al = [](size_t x) { return (x + 255) & ~(size_t)255; };
  const size_t WTB   = 11272192ull * 2;
  const size_t OUTWTB = (size_t)V_ * D_ * 2;
  const size_t HB   = (size_t)B_ * S_ * D_ * 4;
  const size_t XBB  = (size_t)B_ * S_ * D_ * 2;
  const size_t QKVB = (size_t)B_ * S_ * 1536 * 2;
  const size_t QRB  = (size_t)B_ * HQ_ * S_ * 64 * 2;
  const size_t KRB  = (size_t)B_ * HK_ * S_ * 64 * 2;
  const size_t OB   = (size_t)B_ * S_ * D_ * 2;
  const size_t GATEB = (size_t)B_ * S_ * 2816 * 2;
  const size_t TABB = (size_t)S_ * 32 * 2 * 4;

  size_t fixed = al(OUTWTB) + al(HB) + al(XBB) + al(QKVB) + al(QRB) + al(KRB) + al(KRB) +
                 al(OB) + al(GATEB) + al(TABB);
  bool allup = ws_size >= fixed + 8 * al(WTB) + 4096;
  int nslots = allup ? 8 : 1;

  char* p = (char*)d_ws;
  bf16* wT    = (bf16*)p; p += (size_t)nslots * al(WTB);
  bf16* outwT = (bf16*)p; p += al(OUTWTB);
  float* h    = (float*)p; p += al(HB);
  bf16* xb    = (bf16*)p; p += al(XBB);
  bf16* qkv   = (bf16*)p; p += al(QKVB);
  bf16* q_r   = (bf16*)p; p += al(QRB);
  bf16* k_r   = (bf16*)p; p += al(KRB);
  bf16* vTb   = (bf16*)p; p += al(KRB);
  bf16* ob    = (bf16*)p; p += al(OB);
  bf16* gate  = (bf16*)p; p += al(GATEB);
  float* tab  = (float*)p; p += al(TABB);

  const size_t WTS = al(WTB) / 2;
  const size_t OFF_QKV = 0;
  const size_t OFF_WK  = 1024ull * 1024;
  const size_t OFF_WV  = 1280ull * 1024;
  const size_t OFF_WO  = 1572864ull;
  const size_t OFF_W13 = 2621440ull;       // interleaved w1/w3: 5632 rows x 1024
  const size_t OFF_W2  = 8388608ull;

  auto tr = [&](const float* src, size_t srcStride, bf16* dst, size_t dstStride,
                int Kd, int Nd, int layers, int rowMul, int rowAdd) {
    transpose_cvt<<<dim3(Nd / 32, Kd / 32, layers), 256, 0, stream>>>(
        src, dst, Kd, Nd, (long long)srcStride, (long long)dstStride, rowMul, rowAdd);
  };

  ropetab_k<<<128, 256, 0, stream>>>(tab);
  embed_k<<<B_ * S_, 256, 0, stream>>>(tokens, tok_emb, h);
  tr(outw, 0, outwT, 0, 1024, 32000, 1, 1, 0);

  if (allup) {
    tr(wq, 1024 * 1024, wT + OFF_QKV, WTS, 1024, 1024, 8, 1, 0);
    tr(wk, 1024 * 256,  wT + OFF_WK,  WTS, 1024, 256, 8, 1, 0);
    tr(wv, 1024 * 256,  wT + OFF_WV,  WTS, 1024, 256, 8, 1, 0);
    tr(wo, 1024 * 1024, wT + OFF_WO,  WTS, 1024, 1024, 8, 1, 0);
    tr(w1, 1024 * 2816, wT + OFF_W13, WTS, 1024, 2816, 8, 2, 0);
    tr(w3, 1024 * 2816, wT + OFF_W13, WTS, 1024, 2816, 8, 2, 1);
    tr(w2, 2816 * 1024, wT + OFF_W2,  WTS, 2816, 1024, 8, 1, 0);
  }

  for (int l = 0; l < L_; ++l) {
    bf16* wtl = wT + (allup ? (size_t)l * WTS : 0);
    if (!allup) {
      tr(wq + (size_t)l * 1024 * 1024, 0, wtl + OFF_QKV, 0, 1024, 1024, 1, 1, 0);
      tr(wk + (size_t)l * 1024 * 256,  0, wtl + OFF_WK,  0, 1024, 256, 1, 1, 0);
      tr(wv + (size_t)l * 1024 * 256,  0, wtl + OFF_WV,  0, 1024, 256, 1, 1, 0);
      tr(wo + (size_t)l * 1024 * 1024, 0, wtl + OFF_WO,  0, 1024, 1024, 1, 1, 0);
      tr(w1 + (size_t)l * 1024 * 2816, 0, wtl + OFF_W13, 0, 1024, 2816, 1, 2, 0);
      tr(w3 + (size_t)l * 1024 * 2816, 0, wtl + OFF_W13, 0, 1024, 2816, 1, 2, 1);
      tr(w2 + (size_t)l * 2816 * 1024, 0, wtl + OFF_W2,  0, 2816, 1024, 1, 1, 0);
    }

    rmsnorm_k<<<B_ * S_, 256, 0, stream>>>(h, anw + l * D_, xb);
    gemm8_bt<2><<<192, 512, 65536, stream>>>(xb, wtl + OFF_QKV, qkv, nullptr, 1536, 1024);
    qkvpost_k<<<1408, 256, 0, stream>>>(qkv, tab, q_r, k_r, vTb);
    attn_k<<<B_ * HQ_ * (S_ / 64), 256, 0, stream>>>(q_r, k_r, vTb, ob);
    gemm_bt<1, 64><<<dim3(32, 8), 256, 0, stream>>>(ob, wtl + OFF_WO, h, h, 2048, 1024, 1024);
    rmsnorm_k<<<B_ * S_, 256, 0, stream>>>(h, fnw + l * D_, xb);
    gemm8_bt<3><<<704, 512, 65536, stream>>>(xb, wtl + OFF_W13, gate, nullptr, 5632, 1024);
    gemm_bt<1, 64><<<dim3(32, 8), 256, 0, stream>>>(gate, wtl + OFF_W2, h, h, 2048, 1024, 2816);
  }

  rmsnorm_k<<<B_ * S_, 256, 0, stream>>>(h, finw, xb);
  gemm256_bt<0><<<1000, 512, 131072, stream>>>(xb, outwT, d_out, nullptr, 32000, 1024);
}